// Round 2
// baseline (830.944 us; speedup 1.0000x reference)
//
#include <hip/hip_runtime.h>
#include <math.h>

#define NH    8
#define HD    64
#define NTOK  4096   // D*H*W = 16^3
#define CDIM  512
#define NSAMP 27

// ============ Kernel 1: qkv = x @ w_qkv^T, scattered to q/k/v head-major ============
__global__ __launch_bounds__(256) void k_qkv(const float* __restrict__ A,
                                             const float* __restrict__ Wt,
                                             float* __restrict__ qb,
                                             float* __restrict__ kb,
                                             float* __restrict__ vb) {
  __shared__ float As[8][128];
  __shared__ float Bs[8][128];
  const int bm = blockIdx.x, bn = blockIdx.y;
  const int tid = threadIdx.x;
  const int tx = tid & 15, ty = tid >> 4;
  float acc[8][8];
#pragma unroll
  for (int i = 0; i < 8; i++)
#pragma unroll
    for (int j = 0; j < 8; j++) acc[i][j] = 0.f;
  const int r = tid >> 1, c4 = (tid & 1) * 4;
  for (int k0 = 0; k0 < 512; k0 += 8) {
    float4 a4 = *(const float4*)&A[(size_t)(bm * 128 + r) * 512 + k0 + c4];
    float4 b4 = *(const float4*)&Wt[(size_t)(bn * 128 + r) * 512 + k0 + c4];
    As[c4 + 0][r] = a4.x; As[c4 + 1][r] = a4.y; As[c4 + 2][r] = a4.z; As[c4 + 3][r] = a4.w;
    Bs[c4 + 0][r] = b4.x; Bs[c4 + 1][r] = b4.y; Bs[c4 + 2][r] = b4.z; Bs[c4 + 3][r] = b4.w;
    __syncthreads();
#pragma unroll
    for (int kk = 0; kk < 8; kk++) {
      float4 a0 = *(const float4*)&As[kk][ty * 8];
      float4 a1 = *(const float4*)&As[kk][ty * 8 + 4];
      float4 b0 = *(const float4*)&Bs[kk][tx * 4];
      float4 b1 = *(const float4*)&Bs[kk][64 + tx * 4];
      float av[8] = {a0.x, a0.y, a0.z, a0.w, a1.x, a1.y, a1.z, a1.w};
      float bv[8] = {b0.x, b0.y, b0.z, b0.w, b1.x, b1.y, b1.z, b1.w};
#pragma unroll
      for (int i = 0; i < 8; i++)
#pragma unroll
        for (int j = 0; j < 8; j++) acc[i][j] += av[i] * bv[j];
    }
    __syncthreads();
  }
#pragma unroll
  for (int i = 0; i < 8; i++) {
    int n = bm * 128 + ty * 8 + i;
#pragma unroll
    for (int j = 0; j < 8; j++) {
      int m = bn * 128 + ((j < 4) ? (tx * 4 + j) : (64 + tx * 4 + (j - 4)));
      int t = m >> 9;          // 0:q 1:k 2:v
      int h = (m >> 6) & 7;
      int d = m & 63;
      float* dst = (t == 0) ? qb : (t == 1) ? kb : vb;
      dst[((size_t)h * NTOK + n) * 64 + d] = acc[i][j];
    }
  }
}

// ============ Kernel 2: offsets obuf[h][n][j] = x_chunk(n,h) . w_off[j] ============
__global__ __launch_bounds__(256) void k_off(const float* __restrict__ x,
                                             const float* __restrict__ w_off,
                                             float* __restrict__ obuf) {
  __shared__ float xs[512];
  __shared__ float wsT[64][81];
  const int n = blockIdx.x;
  const int tid = threadIdx.x;
  xs[tid] = x[(size_t)n * 512 + tid];
  xs[tid + 256] = x[(size_t)n * 512 + tid + 256];
  for (int t = tid; t < 81 * 64; t += 256) {
    int j = t >> 6, d = t & 63;
    wsT[d][j] = w_off[t];
  }
  __syncthreads();
  for (int m = tid; m < NH * 81; m += 256) {
    int h = m / 81, j = m - h * 81;
    float acc = 0.f;
#pragma unroll
    for (int d = 0; d < 64; d++) acc += xs[h * 64 + d] * wsT[d][j];
    obuf[((size_t)h * NTOK + n) * 81 + j] = acc;
  }
}

// ============ Kernel 3: P[h][n][j] = q . concat(rel_w, rel_h, rel_d)[j] ============
__global__ __launch_bounds__(256) void k_pos(const float* __restrict__ qb,
                                             const float* __restrict__ rel_d,
                                             const float* __restrict__ rel_h,
                                             const float* __restrict__ rel_w,
                                             float* __restrict__ Pbuf) {
  __shared__ float qs[512];
  __shared__ float relT[64][128];   // cols 0..41 rel_w, 42..83 rel_h, 84..125 rel_d
  const int n = blockIdx.x;
  const int tid = threadIdx.x;
  {
    int h = tid >> 6, d = tid & 63;
    qs[tid] = qb[((size_t)h * NTOK + n) * 64 + d];
    int h2 = (tid + 256) >> 6;
    qs[tid + 256] = qb[((size_t)h2 * NTOK + n) * 64 + d];
  }
  for (int t = tid; t < 42 * 64; t += 256) {
    int j = t >> 6, d = t & 63;
    relT[d][j]      = rel_w[t];
    relT[d][42 + j] = rel_h[t];
    relT[d][84 + j] = rel_d[t];
  }
  __syncthreads();
  for (int m = tid; m < NH * 126; m += 256) {
    int h = m / 126, j = m - h * 126;
    float acc = 0.f;
#pragma unroll
    for (int d = 0; d < 64; d++) acc += qs[h * 64 + d] * relT[d][j];
    Pbuf[((size_t)h * NTOK + n) * 126 + j] = acc;
  }
}

// ============ Kernel 4: fused deformable attention (one wave per (h,n)) ============
// R2: single gather pass (k+v fused, v cached in 27 VGPRs), LDS transpose-reduce
// instead of 27x butterfly (was 162 shfl + 162 add per lane -> ~27 wr + 32 rd + 33 add).
__global__ __launch_bounds__(256) void k_attn(const float* __restrict__ qb,
                                              const float* __restrict__ kb,
                                              const float* __restrict__ vb,
                                              const float* __restrict__ obuf,
                                              const float* __restrict__ Pbuf,
                                              float* __restrict__ attb) {
  __shared__ int   s_off[4][NSAMP][8];          // element offsets (idx*64), 16B-aligned rows
  __shared__ float s_cw[4][NSAMP][8];
  __shared__ float red[4][NSAMP * 65];          // row stride 65 -> conflict-free transpose
  __shared__ float s_w[4][NSAMP];
  const int bid = blockIdx.x;
  const int h = bid & 7;                        // head fast-varying -> per-XCD L2 locality
  const int wave = threadIdx.x >> 6;
  const int lane = threadIdx.x & 63;
  const int n = (bid >> 3) * 4 + wave;
  const int z = n >> 8, y = (n >> 4) & 15, xq = n & 15;
  const float qd = qb[((size_t)h * NTOK + n) * 64 + lane];

  if (lane < NSAMP) {
    const int s = lane;
    const float* op = &obuf[((size_t)h * NTOK + n) * 81 + s * 3];
    float oz = op[0], oy = op[1], ox = op[2];
    float pz = (float)(z + (s / 9) - 1) + oz;
    float py = (float)(y + ((s / 3) % 3) - 1) + oy;
    float px = (float)(xq + (s % 3) - 1) + ox;
    float fz = floorf(pz), fy = floorf(py), fx = floorf(px);
    float wz = pz - fz, wy = py - fy, wx = px - fx;
    int z0 = (int)fz, y0 = (int)fy, x0 = (int)fx;
#pragma unroll
    for (int c = 0; c < 8; c++) {
      int dz = (c >> 2) & 1, dy = (c >> 1) & 1, dx = c & 1;
      int zi = z0 + dz, yi = y0 + dy, xi = x0 + dx;
      bool valid = (zi >= 0) && (zi < 16) && (yi >= 0) && (yi < 16) && (xi >= 0) && (xi < 16);
      float w = (dz ? wz : 1.f - wz) * (dy ? wy : 1.f - wy) * (dx ? wx : 1.f - wx);
      int zc = min(max(zi, 0), 15), yc = min(max(yi, 0), 15), xc = min(max(xi, 0), 15);
      s_off[wave][s][c] = ((zc * 16 + yc) * 16 + xc) * 64;
      s_cw[wave][s][c] = valid ? w : 0.f;
    }
  }
  __syncthreads();

  // ---- single gather pass: k-dot partials -> LDS, v samples -> registers ----
  const float* kbh = kb + (size_t)h * NTOK * 64 + lane;
  const float* vbh = vb + (size_t)h * NTOK * 64 + lane;
  float vcache[NSAMP];
#pragma unroll
  for (int s = 0; s < NSAMP; s++) {
    const int*   op = s_off[wave][s];
    const float* wp = s_cw[wave][s];
    float ak = 0.f, av = 0.f;
#pragma unroll
    for (int c = 0; c < 8; c++) {
      int o = op[c];
      float w = wp[c];
      ak += w * kbh[o];
      av += w * vbh[o];
    }
    vcache[s] = av;
    red[wave][s * 65 + lane] = qd * ak;
  }
  __syncthreads();

  // ---- transpose-reduce: 2 lanes per sample sum 32 values each, fold with 1 shfl ----
  float logit = -INFINITY;
  {
    const int s = lane >> 1, half = lane & 1;
    float p0 = 0.f, p1 = 0.f, p2 = 0.f, p3 = 0.f;
    if (s < NSAMP) {
      const float* rp = &red[wave][s * 65 + half * 32];
#pragma unroll
      for (int j = 0; j < 32; j += 4) {
        p0 += rp[j]; p1 += rp[j + 1]; p2 += rp[j + 2]; p3 += rp[j + 3];
      }
    }
    float part = (p0 + p1) + (p2 + p3);
    part += __shfl_xor(part, 1, 64);
    if (s < NSAMP && half == 0) {
      int j = 15 + s - xq;
      int n2 = (z * 16 + xq) * 16 + y;   // q(z, x, y) for rel_h term
      int n3 = (xq * 16 + z) * 16 + y;   // q(x, z, y) for rel_d term
      float pos = Pbuf[((size_t)h * NTOK + n) * 126 + j]
                + Pbuf[((size_t)h * NTOK + n2) * 126 + 42 + j]
                + Pbuf[((size_t)h * NTOK + n3) * 126 + 84 + j];
      logit = part * 0.125f + pos;
    }
  }

  // ---- softmax over the 27 active (even) lanes ----
  float mx = logit;
#pragma unroll
  for (int off = 32; off >= 1; off >>= 1) mx = fmaxf(mx, __shfl_xor(mx, off, 64));
  float e = __expf(logit - mx);            // inactive lanes: exp(-inf) = 0
  float sum = e;
#pragma unroll
  for (int off = 32; off >= 1; off >>= 1) sum += __shfl_xor(sum, off, 64);
  const float inv = 1.f / sum;
  if (logit > -INFINITY * 0.5f && (lane & 1) == 0 && (lane >> 1) < NSAMP)
    s_w[wave][lane >> 1] = e * inv;
  __syncthreads();

  // ---- output: out_c = sum_s w_s * vcache[s] (27 broadcast reads + 27 FMA) ----
  float out = 0.f;
#pragma unroll
  for (int s = 0; s < NSAMP; s++) out += s_w[wave][s] * vcache[s];
  attb[(size_t)n * 512 + h * 64 + lane] = out;
}

// ============ Kernel 5: out = attb @ w_proj^T + b_proj ============
__global__ __launch_bounds__(256) void k_proj(const float* __restrict__ A,
                                              const float* __restrict__ Wt,
                                              const float* __restrict__ bias,
                                              float* __restrict__ out) {
  __shared__ float As[8][128];
  __shared__ float Bs[8][128];
  const int bm = blockIdx.x, bn = blockIdx.y;
  const int tid = threadIdx.x;
  const int tx = tid & 15, ty = tid >> 4;
  float acc[8][8];
#pragma unroll
  for (int i = 0; i < 8; i++)
#pragma unroll
    for (int j = 0; j < 8; j++) acc[i][j] = 0.f;
  const int r = tid >> 1, c4 = (tid & 1) * 4;
  for (int k0 = 0; k0 < 512; k0 += 8) {
    float4 a4 = *(const float4*)&A[(size_t)(bm * 128 + r) * 512 + k0 + c4];
    float4 b4 = *(const float4*)&Wt[(size_t)(bn * 128 + r) * 512 + k0 + c4];
    As[c4 + 0][r] = a4.x; As[c4 + 1][r] = a4.y; As[c4 + 2][r] = a4.z; As[c4 + 3][r] = a4.w;
    Bs[c4 + 0][r] = b4.x; Bs[c4 + 1][r] = b4.y; Bs[c4 + 2][r] = b4.z; Bs[c4 + 3][r] = b4.w;
    __syncthreads();
#pragma unroll
    for (int kk = 0; kk < 8; kk++) {
      float4 a0 = *(const float4*)&As[kk][ty * 8];
      float4 a1 = *(const float4*)&As[kk][ty * 8 + 4];
      float4 b0 = *(const float4*)&Bs[kk][tx * 4];
      float4 b1 = *(const float4*)&Bs[kk][64 + tx * 4];
      float av[8] = {a0.x, a0.y, a0.z, a0.w, a1.x, a1.y, a1.z, a1.w};
      float bv[8] = {b0.x, b0.y, b0.z, b0.w, b1.x, b1.y, b1.z, b1.w};
#pragma unroll
      for (int i = 0; i < 8; i++)
#pragma unroll
        for (int j = 0; j < 8; j++) acc[i][j] += av[i] * bv[j];
    }
    __syncthreads();
  }
#pragma unroll
  for (int i = 0; i < 8; i++) {
    int n = bm * 128 + ty * 8 + i;
#pragma unroll
    for (int j = 0; j < 8; j++) {
      int m = bn * 128 + ((j < 4) ? (tx * 4 + j) : (64 + tx * 4 + (j - 4)));
      out[(size_t)n * 512 + m] = acc[i][j] + bias[m];
    }
  }
}

extern "C" void kernel_launch(void* const* d_in, const int* in_sizes, int n_in,
                              void* d_out, int out_size, void* d_ws, size_t ws_size,
                              hipStream_t stream) {
  const float* x      = (const float*)d_in[0];
  const float* w_qkv  = (const float*)d_in[1];
  const float* w_proj = (const float*)d_in[2];
  const float* b_proj = (const float*)d_in[3];
  const float* w_off  = (const float*)d_in[4];
  const float* rel_d  = (const float*)d_in[5];
  const float* rel_h  = (const float*)d_in[6];
  const float* rel_w  = (const float*)d_in[7];

  float* ws   = (float*)d_ws;
  float* qb   = ws;                                  // 8*4096*64
  float* kb   = qb + (size_t)NH * NTOK * 64;
  float* vb   = kb + (size_t)NH * NTOK * 64;
  float* ob   = vb + (size_t)NH * NTOK * 64;         // 8*4096*81
  float* Pb   = ob + (size_t)NH * NTOK * 81;         // 8*4096*126
  float* attb = Pb + (size_t)NH * NTOK * 126;        // 4096*512
  float* out  = (float*)d_out;

  k_qkv <<<dim3(32, 12), dim3(256), 0, stream>>>(x, w_qkv, qb, kb, vb);
  k_off <<<dim3(4096),  dim3(256), 0, stream>>>(x, w_off, ob);
  k_pos <<<dim3(4096),  dim3(256), 0, stream>>>(qb, rel_d, rel_h, rel_w, Pb);
  k_attn<<<dim3(8192),  dim3(256), 0, stream>>>(qb, kb, vb, ob, Pb, attb);
  k_proj<<<dim3(32, 4), dim3(256), 0, stream>>>(attb, w_proj, b_proj, out);
}

// Round 3
// 442.154 us; speedup vs baseline: 1.8793x; 1.8793x over previous
//
#include <hip/hip_runtime.h>
#include <math.h>
#include <stdint.h>

#define NH    8
#define HD    64
#define NTOK  4096   // D*H*W = 16^3
#define CDIM  512
#define NSAMP 27

// float -> bf16 bits with round-to-nearest-even
__device__ __forceinline__ uint32_t bf16b(float f) {
  uint32_t u = __float_as_uint(f);
  return (u + 0x7fffu + ((u >> 16) & 1u)) >> 16;
}

// Full 64-lane sum via DPP (pure VALU, no LDS): result broadcast via readlane(63)
__device__ __forceinline__ float wave_sum_bcast(float x) {
#define DPP_STEP(ctrl, rmask)                                                   \
  { int t = __builtin_amdgcn_update_dpp(0, __float_as_int(x), ctrl, rmask, 0xf, \
                                        true);                                  \
    x += __int_as_float(t); }
  DPP_STEP(0x111, 0xf)  // row_shr:1
  DPP_STEP(0x112, 0xf)  // row_shr:2
  DPP_STEP(0x114, 0xf)  // row_shr:4
  DPP_STEP(0x118, 0xf)  // row_shr:8  -> lane15 of each row = row sum
  DPP_STEP(0x142, 0xa)  // row_bcast:15 into rows 1,3
  DPP_STEP(0x143, 0xc)  // row_bcast:31 into rows 2,3 -> lane63 = total
#undef DPP_STEP
  return __int_as_float(__builtin_amdgcn_readlane(__float_as_int(x), 63));
}

// ============ Kernel 1: qkv = x @ w_qkv^T; q -> fp32, k/v -> packed bf16 dword ============
__global__ __launch_bounds__(256) void k_qkv(const float* __restrict__ A,
                                             const float* __restrict__ Wt,
                                             float* __restrict__ qb,
                                             uint32_t* __restrict__ kvb) {
  __shared__ float As[8][128];
  __shared__ float Bs[8][128];
  const int bm = blockIdx.x, bn = blockIdx.y;
  const int tid = threadIdx.x;
  const int tx = tid & 15, ty = tid >> 4;
  float acc[8][8];
#pragma unroll
  for (int i = 0; i < 8; i++)
#pragma unroll
    for (int j = 0; j < 8; j++) acc[i][j] = 0.f;
  const int r = tid >> 1, c4 = (tid & 1) * 4;
  for (int k0 = 0; k0 < 512; k0 += 8) {
    float4 a4 = *(const float4*)&A[(size_t)(bm * 128 + r) * 512 + k0 + c4];
    float4 b4 = *(const float4*)&Wt[(size_t)(bn * 128 + r) * 512 + k0 + c4];
    As[c4 + 0][r] = a4.x; As[c4 + 1][r] = a4.y; As[c4 + 2][r] = a4.z; As[c4 + 3][r] = a4.w;
    Bs[c4 + 0][r] = b4.x; Bs[c4 + 1][r] = b4.y; Bs[c4 + 2][r] = b4.z; Bs[c4 + 3][r] = b4.w;
    __syncthreads();
#pragma unroll
    for (int kk = 0; kk < 8; kk++) {
      float4 a0 = *(const float4*)&As[kk][ty * 8];
      float4 a1 = *(const float4*)&As[kk][ty * 8 + 4];
      float4 b0 = *(const float4*)&Bs[kk][tx * 4];
      float4 b1 = *(const float4*)&Bs[kk][64 + tx * 4];
      float av[8] = {a0.x, a0.y, a0.z, a0.w, a1.x, a1.y, a1.z, a1.w};
      float bv[8] = {b0.x, b0.y, b0.z, b0.w, b1.x, b1.y, b1.z, b1.w};
#pragma unroll
      for (int i = 0; i < 8; i++)
#pragma unroll
        for (int j = 0; j < 8; j++) acc[i][j] += av[i] * bv[j];
    }
    __syncthreads();
  }
  unsigned short* kvh16 = (unsigned short*)kvb;
#pragma unroll
  for (int i = 0; i < 8; i++) {
    int n = bm * 128 + ty * 8 + i;
#pragma unroll
    for (int j = 0; j < 8; j++) {
      int m = bn * 128 + ((j < 4) ? (tx * 4 + j) : (64 + tx * 4 + (j - 4)));
      int t = m >> 9;          // 0:q 1:k 2:v
      int h = (m >> 6) & 7;
      int d = m & 63;
      size_t idx = ((size_t)h * NTOK + n) * 64 + d;
      if (t == 0) {
        qb[idx] = acc[i][j];
      } else {
        // k -> low 16 bits, v -> high 16 bits of kvb[idx] (byte-granular stores
        // from different blocks to different halves of the same dword are safe)
        kvh16[idx * 2 + (t - 1)] = (unsigned short)bf16b(acc[i][j]);
      }
    }
  }
}

// ============ Kernel 2: offsets obuf[h][n][j] = x_chunk(n,h) . w_off[j] ============
__global__ __launch_bounds__(256) void k_off(const float* __restrict__ x,
                                             const float* __restrict__ w_off,
                                             float* __restrict__ obuf) {
  __shared__ float xs[512];
  __shared__ float wsT[64][81];
  const int n = blockIdx.x;
  const int tid = threadIdx.x;
  xs[tid] = x[(size_t)n * 512 + tid];
  xs[tid + 256] = x[(size_t)n * 512 + tid + 256];
  for (int t = tid; t < 81 * 64; t += 256) {
    int j = t >> 6, d = t & 63;
    wsT[d][j] = w_off[t];
  }
  __syncthreads();
  for (int m = tid; m < NH * 81; m += 256) {
    int h = m / 81, j = m - h * 81;
    float acc = 0.f;
#pragma unroll
    for (int d = 0; d < 64; d++) acc += xs[h * 64 + d] * wsT[d][j];
    obuf[((size_t)h * NTOK + n) * 81 + j] = acc;
  }
}

// ============ Kernel 3: P[h][n][j] = q . concat(rel_w, rel_h, rel_d)[j] ============
__global__ __launch_bounds__(256) void k_pos(const float* __restrict__ qb,
                                             const float* __restrict__ rel_d,
                                             const float* __restrict__ rel_h,
                                             const float* __restrict__ rel_w,
                                             float* __restrict__ Pbuf) {
  __shared__ float qs[512];
  __shared__ float relT[64][128];   // cols 0..41 rel_w, 42..83 rel_h, 84..125 rel_d
  const int n = blockIdx.x;
  const int tid = threadIdx.x;
  {
    int h = tid >> 6, d = tid & 63;
    qs[tid] = qb[((size_t)h * NTOK + n) * 64 + d];
    int h2 = (tid + 256) >> 6;
    qs[tid + 256] = qb[((size_t)h2 * NTOK + n) * 64 + d];
  }
  for (int t = tid; t < 42 * 64; t += 256) {
    int j = t >> 6, d = t & 63;
    relT[d][j]      = rel_w[t];
    relT[d][42 + j] = rel_h[t];
    relT[d][84 + j] = rel_d[t];
  }
  __syncthreads();
  for (int m = tid; m < NH * 126; m += 256) {
    int h = m / 126, j = m - h * 126;
    float acc = 0.f;
#pragma unroll
    for (int d = 0; d < 64; d++) acc += qs[h * 64 + d] * relT[d][j];
    Pbuf[((size_t)h * NTOK + n) * 126 + j] = acc;
  }
}

// ============ Kernel 4: fused deformable attention (one wave per (h,n)) ============
// R3: single gather pass over packed bf16 (k,v) dwords; v-samples parked in LDS as
// bf16 pairs; per-sample reduction via DPP (no LDS shuffles); barrier-free
// (all LDS producer/consumer pairs are within one wave).
__global__ __launch_bounds__(256) void k_attn(const float* __restrict__ qb,
                                              const uint32_t* __restrict__ kvb,
                                              const float* __restrict__ obuf,
                                              const float* __restrict__ Pbuf,
                                              float* __restrict__ attb) {
  __shared__ int      s_off[4][NSAMP][8];   // voxel*64 element offsets, 32B rows
  __shared__ float    s_cw[4][NSAMP][8];
  __shared__ uint32_t vpair[4][14][64];     // (bf16 v[2p] | bf16 v[2p+1]<<16) per channel
  __shared__ float    s_w[4][28];           // softmax weights, [27] = 0
  const int bid = blockIdx.x;
  const int h = bid & 7;                    // head fast-varying -> per-XCD L2 locality
  const int wave = threadIdx.x >> 6;
  const int lane = threadIdx.x & 63;
  const int n = (bid >> 3) * 4 + wave;
  const int z = n >> 8, y = (n >> 4) & 15, xq = n & 15;
  const float qd = qb[((size_t)h * NTOK + n) * 64 + lane];
  const uint32_t* kvh = kvb + (size_t)h * NTOK * 64;

  if (lane < NSAMP) {
    const int s = lane;
    const float* op = &obuf[((size_t)h * NTOK + n) * 81 + s * 3];
    float oz = op[0], oy = op[1], ox = op[2];
    float pz = (float)(z + (s / 9) - 1) + oz;
    float py = (float)(y + ((s / 3) % 3) - 1) + oy;
    float px = (float)(xq + (s % 3) - 1) + ox;
    float fz = floorf(pz), fy = floorf(py), fx = floorf(px);
    float wz = pz - fz, wy = py - fy, wx = px - fx;
    int z0 = (int)fz, y0 = (int)fy, x0 = (int)fx;
    int   oarr[8];
    float warr[8];
#pragma unroll
    for (int c = 0; c < 8; c++) {
      int dz = (c >> 2) & 1, dy = (c >> 1) & 1, dx = c & 1;
      int zi = z0 + dz, yi = y0 + dy, xi = x0 + dx;
      bool valid = (zi >= 0) && (zi < 16) && (yi >= 0) && (yi < 16) && (xi >= 0) && (xi < 16);
      float w = (dz ? wz : 1.f - wz) * (dy ? wy : 1.f - wy) * (dx ? wx : 1.f - wx);
      int zc = min(max(zi, 0), 15), yc = min(max(yi, 0), 15), xc = min(max(xi, 0), 15);
      oarr[c] = ((zc * 16 + yc) * 16 + xc) * 64;
      warr[c] = valid ? w : 0.f;
    }
    *(int4*)&s_off[wave][s][0]   = make_int4(oarr[0], oarr[1], oarr[2], oarr[3]);
    *(int4*)&s_off[wave][s][4]   = make_int4(oarr[4], oarr[5], oarr[6], oarr[7]);
    *(float4*)&s_cw[wave][s][0]  = make_float4(warr[0], warr[1], warr[2], warr[3]);
    *(float4*)&s_cw[wave][s][4]  = make_float4(warr[4], warr[5], warr[6], warr[7]);
  }
  // no __syncthreads: producer lanes and consumers are the same wave (in-order ds)

  // ---- single gather pass: k-dot via DPP reduce, v-sample -> LDS bf16 pairs ----
  float mydot = 0.f;
  float av_even = 0.f;
#pragma unroll 2
  for (int s = 0; s < NSAMP; s++) {
    int4   o0 = *(const int4*)&s_off[wave][s][0];
    int4   o1 = *(const int4*)&s_off[wave][s][4];
    float4 w0 = *(const float4*)&s_cw[wave][s][0];
    float4 w1 = *(const float4*)&s_cw[wave][s][4];
    float ak = 0.f, av = 0.f;
    uint32_t p;
#define CORNER(OV, WV)                                             \
    p = kvh[(uint32_t)(OV + lane)];                                \
    ak = fmaf(WV, __uint_as_float(p << 16), ak);                   \
    av = fmaf(WV, __uint_as_float(p & 0xffff0000u), av);
    CORNER(o0.x, w0.x) CORNER(o0.y, w0.y) CORNER(o0.z, w0.z) CORNER(o0.w, w0.w)
    CORNER(o1.x, w1.x) CORNER(o1.y, w1.y) CORNER(o1.z, w1.z) CORNER(o1.w, w1.w)
#undef CORNER
    float tot = wave_sum_bcast(qd * ak);
    mydot = (lane == s) ? tot : mydot;
    if (s & 1)
      vpair[wave][s >> 1][lane] = bf16b(av_even) | (bf16b(av) << 16);
    else
      av_even = av;
  }
  vpair[wave][13][lane] = bf16b(av_even);   // sample 26 low half, 0 high half

  // ---- logits + pos (lanes 0..26) ----
  float logit = -INFINITY;
  if (lane < NSAMP) {
    int j = 15 + lane - xq;
    int n2 = (z * 16 + xq) * 16 + y;   // q(z, x, y) for rel_h term
    int n3 = (xq * 16 + z) * 16 + y;   // q(x, z, y) for rel_d term
    float pos = Pbuf[((size_t)h * NTOK + n) * 126 + j]
              + Pbuf[((size_t)h * NTOK + n2) * 126 + 42 + j]
              + Pbuf[((size_t)h * NTOK + n3) * 126 + 84 + j];
    logit = mydot * 0.125f + pos;
  }

  // ---- softmax over 27 (once per wave; shfl cost negligible) ----
  float mx = logit;
#pragma unroll
  for (int off = 32; off >= 1; off >>= 1) mx = fmaxf(mx, __shfl_xor(mx, off, 64));
  float e = __expf(logit - mx);            // lanes >= 27: exp(-inf) = 0
  float sum = e;
#pragma unroll
  for (int off = 32; off >= 1; off >>= 1) sum += __shfl_xor(sum, off, 64);
  const float inv = 1.f / sum;
  if (lane < 28) s_w[wave][lane] = e * inv;   // lane 27 writes 0

  // ---- output: out_c = sum_s w_s * v_s[c], from LDS bf16 pairs ----
  float out = 0.f;
#pragma unroll
  for (int p2 = 0; p2 < 14; p2++) {
    uint32_t pv = vpair[wave][p2][lane];
    float2 wp = *(const float2*)&s_w[wave][2 * p2];
    out = fmaf(wp.x, __uint_as_float(pv << 16), out);
    out = fmaf(wp.y, __uint_as_float(pv & 0xffff0000u), out);
  }
  attb[(size_t)n * 512 + h * 64 + lane] = out;
}

// ============ Kernel 5: out = attb @ w_proj^T + b_proj ============
__global__ __launch_bounds__(256) void k_proj(const float* __restrict__ A,
                                              const float* __restrict__ Wt,
                                              const float* __restrict__ bias,
                                              float* __restrict__ out) {
  __shared__ float As[8][128];
  __shared__ float Bs[8][128];
  const int bm = blockIdx.x, bn = blockIdx.y;
  const int tid = threadIdx.x;
  const int tx = tid & 15, ty = tid >> 4;
  float acc[8][8];
#pragma unroll
  for (int i = 0; i < 8; i++)
#pragma unroll
    for (int j = 0; j < 8; j++) acc[i][j] = 0.f;
  const int r = tid >> 1, c4 = (tid & 1) * 4;
  for (int k0 = 0; k0 < 512; k0 += 8) {
    float4 a4 = *(const float4*)&A[(size_t)(bm * 128 + r) * 512 + k0 + c4];
    float4 b4 = *(const float4*)&Wt[(size_t)(bn * 128 + r) * 512 + k0 + c4];
    As[c4 + 0][r] = a4.x; As[c4 + 1][r] = a4.y; As[c4 + 2][r] = a4.z; As[c4 + 3][r] = a4.w;
    Bs[c4 + 0][r] = b4.x; Bs[c4 + 1][r] = b4.y; Bs[c4 + 2][r] = b4.z; Bs[c4 + 3][r] = b4.w;
    __syncthreads();
#pragma unroll
    for (int kk = 0; kk < 8; kk++) {
      float4 a0 = *(const float4*)&As[kk][ty * 8];
      float4 a1 = *(const float4*)&As[kk][ty * 8 + 4];
      float4 b0 = *(const float4*)&Bs[kk][tx * 4];
      float4 b1 = *(const float4*)&Bs[kk][64 + tx * 4];
      float av[8] = {a0.x, a0.y, a0.z, a0.w, a1.x, a1.y, a1.z, a1.w};
      float bv[8] = {b0.x, b0.y, b0.z, b0.w, b1.x, b1.y, b1.z, b1.w};
#pragma unroll
      for (int i = 0; i < 8; i++)
#pragma unroll
        for (int j = 0; j < 8; j++) acc[i][j] += av[i] * bv[j];
    }
    __syncthreads();
  }
#pragma unroll
  for (int i = 0; i < 8; i++) {
    int n = bm * 128 + ty * 8 + i;
#pragma unroll
    for (int j = 0; j < 8; j++) {
      int m = bn * 128 + ((j < 4) ? (tx * 4 + j) : (64 + tx * 4 + (j - 4)));
      out[(size_t)n * 512 + m] = acc[i][j] + bias[m];
    }
  }
}

extern "C" void kernel_launch(void* const* d_in, const int* in_sizes, int n_in,
                              void* d_out, int out_size, void* d_ws, size_t ws_size,
                              hipStream_t stream) {
  const float* x      = (const float*)d_in[0];
  const float* w_qkv  = (const float*)d_in[1];
  const float* w_proj = (const float*)d_in[2];
  const float* b_proj = (const float*)d_in[3];
  const float* w_off  = (const float*)d_in[4];
  const float* rel_d  = (const float*)d_in[5];
  const float* rel_h  = (const float*)d_in[6];
  const float* rel_w  = (const float*)d_in[7];

  float* ws    = (float*)d_ws;
  float*    qb   = ws;                                   // 8*4096*64 f32
  uint32_t* kvb  = (uint32_t*)(qb + (size_t)NH * NTOK * 64);  // 8*4096*64 u32
  float*    ob   = (float*)(kvb + (size_t)NH * NTOK * 64);    // 8*4096*81
  float*    Pb   = ob + (size_t)NH * NTOK * 81;          // 8*4096*126
  float*    attb = Pb + (size_t)NH * NTOK * 126;         // 4096*512
  float*    out  = (float*)d_out;

  k_qkv <<<dim3(32, 12), dim3(256), 0, stream>>>(x, w_qkv, qb, kvb);
  k_off <<<dim3(4096),  dim3(256), 0, stream>>>(x, w_off, ob);
  k_pos <<<dim3(4096),  dim3(256), 0, stream>>>(qb, rel_d, rel_h, rel_w, Pb);
  k_attn<<<dim3(8192),  dim3(256), 0, stream>>>(qb, kvb, ob, Pb, attb);
  k_proj<<<dim3(32, 4), dim3(256), 0, stream>>>(attb, w_proj, b_proj, out);
}

// Round 4
// 309.200 us; speedup vs baseline: 2.6874x; 1.4300x over previous
//
#include <hip/hip_runtime.h>
#include <math.h>
#include <stdint.h>

#define NH    8
#define HD    64
#define NTOK  4096   // D*H*W = 16^3
#define CDIM  512
#define NSAMP 27

typedef __attribute__((ext_vector_type(8))) short short8;
typedef __attribute__((ext_vector_type(4))) float floatx4;
typedef unsigned short ushort_t;

// float -> bf16 bits with round-to-nearest-even
__device__ __forceinline__ uint32_t bf16b(float f) {
  uint32_t u = __float_as_uint(f);
  return (u + 0x7fffu + ((u >> 16) & 1u)) >> 16;
}

// Full 64-lane sum via DPP (pure VALU, no LDS): result broadcast via readlane(63)
__device__ __forceinline__ float wave_sum_bcast(float x) {
#define DPP_STEP(ctrl, rmask)                                                   \
  { int t = __builtin_amdgcn_update_dpp(0, __float_as_int(x), ctrl, rmask, 0xf, \
                                        true);                                  \
    x += __int_as_float(t); }
  DPP_STEP(0x111, 0xf)  // row_shr:1
  DPP_STEP(0x112, 0xf)  // row_shr:2
  DPP_STEP(0x114, 0xf)  // row_shr:4
  DPP_STEP(0x118, 0xf)  // row_shr:8  -> lane15 of each row = row sum
  DPP_STEP(0x142, 0xa)  // row_bcast:15 into rows 1,3
  DPP_STEP(0x143, 0xc)  // row_bcast:31 into rows 2,3 -> lane63 = total
#undef DPP_STEP
  return __int_as_float(__builtin_amdgcn_readlane(__float_as_int(x), 63));
}

// ============ Kernel 0: fp32 -> bf16 conversion for x, w_qkv, w_proj ============
__global__ __launch_bounds__(256) void k_cvt(const float4* __restrict__ x,
                                             const float4* __restrict__ wq,
                                             const float4* __restrict__ wp,
                                             ushort_t* __restrict__ xb,
                                             ushort_t* __restrict__ wqb,
                                             ushort_t* __restrict__ wpb) {
  int i = blockIdx.x * 256 + threadIdx.x;   // 0 .. 786431 float4s
  const float4* src; ushort_t* dst; int off;
  if (i < 524288)      { src = x;  dst = xb;  off = i; }
  else if (i < 720896) { src = wq; dst = wqb; off = i - 524288; }
  else                 { src = wp; dst = wpb; off = i - 720896; }
  float4 v = src[off];
  ushort4 o = make_ushort4((ushort_t)bf16b(v.x), (ushort_t)bf16b(v.y),
                           (ushort_t)bf16b(v.z), (ushort_t)bf16b(v.w));
  *(ushort4*)&dst[(size_t)off * 4] = o;
}

// ============ Kernel 1: qkv GEMM via MFMA bf16 ============
// C(4096x1536) = Abf(4096x512) @ Btbf(1536x512)^T ; epilogue scatters
// q -> fp32 head-major, k/v -> packed bf16 halves of kvb dwords.
__global__ __launch_bounds__(256) void k_qkv(const ushort_t* __restrict__ Abf,
                                             const ushort_t* __restrict__ Btbf,
                                             float* __restrict__ qb,
                                             uint32_t* __restrict__ kvb) {
  __shared__ __align__(16) ushort_t As[128 * 32];
  __shared__ __align__(16) ushort_t Bs[128 * 32];
  const int tid = threadIdx.x;
  const int wave = tid >> 6, lane = tid & 63;
  const int wr = wave >> 1, wc = wave & 1;
  const int m15 = lane & 15, quad = lane >> 4;
  const int bm = blockIdx.x, bn = blockIdx.y;
  floatx4 acc[4][4];
#pragma unroll
  for (int i = 0; i < 4; i++)
#pragma unroll
    for (int j = 0; j < 4; j++) acc[i][j] = {0.f, 0.f, 0.f, 0.f};

  const int r0 = tid >> 2, c0 = (tid & 3) * 8;   // chunk tid: rows 0..63
  const int r1 = r0 + 64;                        // chunk tid+256: rows 64..127
  for (int k0 = 0; k0 < 512; k0 += 32) {
    *(uint4*)&As[r0 * 32 + c0] = *(const uint4*)&Abf[(size_t)(bm * 128 + r0) * 512 + k0 + c0];
    *(uint4*)&As[r1 * 32 + c0] = *(const uint4*)&Abf[(size_t)(bm * 128 + r1) * 512 + k0 + c0];
    *(uint4*)&Bs[r0 * 32 + c0] = *(const uint4*)&Btbf[(size_t)(bn * 128 + r0) * 512 + k0 + c0];
    *(uint4*)&Bs[r1 * 32 + c0] = *(const uint4*)&Btbf[(size_t)(bn * 128 + r1) * 512 + k0 + c0];
    __syncthreads();
    short8 af[4], bf[4];
#pragma unroll
    for (int i = 0; i < 4; i++)
      af[i] = *(const short8*)&As[(wr * 64 + i * 16 + m15) * 32 + quad * 8];
#pragma unroll
    for (int j = 0; j < 4; j++)
      bf[j] = *(const short8*)&Bs[(wc * 64 + j * 16 + m15) * 32 + quad * 8];
#pragma unroll
    for (int i = 0; i < 4; i++)
#pragma unroll
      for (int j = 0; j < 4; j++)
        acc[i][j] = __builtin_amdgcn_mfma_f32_16x16x32_bf16(af[i], bf[j], acc[i][j], 0, 0, 0);
    __syncthreads();
  }

  ushort_t* kvh16 = (ushort_t*)kvb;
#pragma unroll
  for (int i = 0; i < 4; i++)
#pragma unroll
    for (int j = 0; j < 4; j++) {
      int col = bn * 128 + wc * 64 + j * 16 + m15;
      int t = col >> 9;          // 0:q 1:k 2:v
      int h = (col >> 6) & 7;
      int d = col & 63;
#pragma unroll
      for (int r = 0; r < 4; r++) {
        int row = bm * 128 + wr * 64 + i * 16 + quad * 4 + r;
        size_t idx = ((size_t)h * NTOK + row) * 64 + d;
        float v = acc[i][j][r];
        if (t == 0) qb[idx] = v;
        else kvh16[idx * 2 + (t - 1)] = (ushort_t)bf16b(v);
      }
    }
}

// ============ Kernel 2: offsets obuf[h][n][j] = x_chunk(n,h) . w_off[j] ============
__global__ __launch_bounds__(256) void k_off(const float* __restrict__ x,
                                             const float* __restrict__ w_off,
                                             float* __restrict__ obuf) {
  __shared__ float xs[512];
  __shared__ float wsT[64][81];
  const int n = blockIdx.x;
  const int tid = threadIdx.x;
  xs[tid] = x[(size_t)n * 512 + tid];
  xs[tid + 256] = x[(size_t)n * 512 + tid + 256];
  for (int t = tid; t < 81 * 64; t += 256) {
    int j = t >> 6, d = t & 63;
    wsT[d][j] = w_off[t];
  }
  __syncthreads();
  for (int m = tid; m < NH * 81; m += 256) {
    int h = m / 81, j = m - h * 81;
    float acc = 0.f;
#pragma unroll
    for (int d = 0; d < 64; d++) acc += xs[h * 64 + d] * wsT[d][j];
    obuf[((size_t)h * NTOK + n) * 81 + j] = acc;
  }
}

// ============ Kernel 3: P[h][n][j] = q . concat(rel_w, rel_h, rel_d)[j] ============
__global__ __launch_bounds__(256) void k_pos(const float* __restrict__ qb,
                                             const float* __restrict__ rel_d,
                                             const float* __restrict__ rel_h,
                                             const float* __restrict__ rel_w,
                                             float* __restrict__ Pbuf) {
  __shared__ float qs[512];
  __shared__ float relT[64][128];   // cols 0..41 rel_w, 42..83 rel_h, 84..125 rel_d
  const int n = blockIdx.x;
  const int tid = threadIdx.x;
  {
    int h = tid >> 6, d = tid & 63;
    qs[tid] = qb[((size_t)h * NTOK + n) * 64 + d];
    int h2 = (tid + 256) >> 6;
    qs[tid + 256] = qb[((size_t)h2 * NTOK + n) * 64 + d];
  }
  for (int t = tid; t < 42 * 64; t += 256) {
    int j = t >> 6, d = t & 63;
    relT[d][j]      = rel_w[t];
    relT[d][42 + j] = rel_h[t];
    relT[d][84 + j] = rel_d[t];
  }
  __syncthreads();
  for (int m = tid; m < NH * 126; m += 256) {
    int h = m / 126, j = m - h * 126;
    float acc = 0.f;
#pragma unroll
    for (int d = 0; d < 64; d++) acc += qs[h * 64 + d] * relT[d][j];
    Pbuf[((size_t)h * NTOK + n) * 126 + j] = acc;
  }
}

// ============ Kernel 4: fused deformable attention (one wave per (h,n)) ============
__global__ __launch_bounds__(256) void k_attn(const float* __restrict__ qb,
                                              const uint32_t* __restrict__ kvb,
                                              const float* __restrict__ obuf,
                                              const float* __restrict__ Pbuf,
                                              ushort_t* __restrict__ attb16) {
  __shared__ int      s_off[4][NSAMP][8];
  __shared__ float    s_cw[4][NSAMP][8];
  __shared__ uint32_t vpair[4][14][64];
  __shared__ float    s_w[4][28];
  const int bid = blockIdx.x;
  const int h = bid & 7;
  const int wave = threadIdx.x >> 6;
  const int lane = threadIdx.x & 63;
  const int n = (bid >> 3) * 4 + wave;
  const int z = n >> 8, y = (n >> 4) & 15, xq = n & 15;
  const float qd = qb[((size_t)h * NTOK + n) * 64 + lane];
  const uint32_t* kvh = kvb + (size_t)h * NTOK * 64;

  if (lane < NSAMP) {
    const int s = lane;
    const float* op = &obuf[((size_t)h * NTOK + n) * 81 + s * 3];
    float oz = op[0], oy = op[1], ox = op[2];
    float pz = (float)(z + (s / 9) - 1) + oz;
    float py = (float)(y + ((s / 3) % 3) - 1) + oy;
    float px = (float)(xq + (s % 3) - 1) + ox;
    float fz = floorf(pz), fy = floorf(py), fx = floorf(px);
    float wz = pz - fz, wy = py - fy, wx = px - fx;
    int z0 = (int)fz, y0 = (int)fy, x0 = (int)fx;
    int   oarr[8];
    float warr[8];
#pragma unroll
    for (int c = 0; c < 8; c++) {
      int dz = (c >> 2) & 1, dy = (c >> 1) & 1, dx = c & 1;
      int zi = z0 + dz, yi = y0 + dy, xi = x0 + dx;
      bool valid = (zi >= 0) && (zi < 16) && (yi >= 0) && (yi < 16) && (xi >= 0) && (xi < 16);
      float w = (dz ? wz : 1.f - wz) * (dy ? wy : 1.f - wy) * (dx ? wx : 1.f - wx);
      int zc = min(max(zi, 0), 15), yc = min(max(yi, 0), 15), xc = min(max(xi, 0), 15);
      oarr[c] = ((zc * 16 + yc) * 16 + xc) * 64;
      warr[c] = valid ? w : 0.f;
    }
    *(int4*)&s_off[wave][s][0]   = make_int4(oarr[0], oarr[1], oarr[2], oarr[3]);
    *(int4*)&s_off[wave][s][4]   = make_int4(oarr[4], oarr[5], oarr[6], oarr[7]);
    *(float4*)&s_cw[wave][s][0]  = make_float4(warr[0], warr[1], warr[2], warr[3]);
    *(float4*)&s_cw[wave][s][4]  = make_float4(warr[4], warr[5], warr[6], warr[7]);
  }
  // no __syncthreads: producers/consumers are the same wave (in-order ds)

  float mydot = 0.f;
  float av_even = 0.f;
#pragma unroll 2
  for (int s = 0; s < NSAMP; s++) {
    int4   o0 = *(const int4*)&s_off[wave][s][0];
    int4   o1 = *(const int4*)&s_off[wave][s][4];
    float4 w0 = *(const float4*)&s_cw[wave][s][0];
    float4 w1 = *(const float4*)&s_cw[wave][s][4];
    float ak = 0.f, av = 0.f;
    uint32_t p;
#define CORNER(OV, WV)                                             \
    p = kvh[(uint32_t)(OV + lane)];                                \
    ak = fmaf(WV, __uint_as_float(p << 16), ak);                   \
    av = fmaf(WV, __uint_as_float(p & 0xffff0000u), av);
    CORNER(o0.x, w0.x) CORNER(o0.y, w0.y) CORNER(o0.z, w0.z) CORNER(o0.w, w0.w)
    CORNER(o1.x, w1.x) CORNER(o1.y, w1.y) CORNER(o1.z, w1.z) CORNER(o1.w, w1.w)
#undef CORNER
    float tot = wave_sum_bcast(qd * ak);
    mydot = (lane == s) ? tot : mydot;
    if (s & 1)
      vpair[wave][s >> 1][lane] = bf16b(av_even) | (bf16b(av) << 16);
    else
      av_even = av;
  }
  vpair[wave][13][lane] = bf16b(av_even);

  float logit = -INFINITY;
  if (lane < NSAMP) {
    int j = 15 + lane - xq;
    int n2 = (z * 16 + xq) * 16 + y;
    int n3 = (xq * 16 + z) * 16 + y;
    float pos = Pbuf[((size_t)h * NTOK + n) * 126 + j]
              + Pbuf[((size_t)h * NTOK + n2) * 126 + 42 + j]
              + Pbuf[((size_t)h * NTOK + n3) * 126 + 84 + j];
    logit = mydot * 0.125f + pos;
  }

  float mx = logit;
#pragma unroll
  for (int off = 32; off >= 1; off >>= 1) mx = fmaxf(mx, __shfl_xor(mx, off, 64));
  float e = __expf(logit - mx);
  float sum = e;
#pragma unroll
  for (int off = 32; off >= 1; off >>= 1) sum += __shfl_xor(sum, off, 64);
  const float inv = 1.f / sum;
  if (lane < 28) s_w[wave][lane] = e * inv;

  float out = 0.f;
#pragma unroll
  for (int p2 = 0; p2 < 14; p2++) {
    uint32_t pv = vpair[wave][p2][lane];
    float2 wp = *(const float2*)&s_w[wave][2 * p2];
    out = fmaf(wp.x, __uint_as_float(pv << 16), out);
    out = fmaf(wp.y, __uint_as_float(pv & 0xffff0000u), out);
  }
  attb16[(size_t)n * 512 + h * 64 + lane] = (ushort_t)bf16b(out);
}

// ============ Kernel 5: proj GEMM via MFMA bf16: out = attb @ w_proj^T + b ============
__global__ __launch_bounds__(256) void k_proj(const ushort_t* __restrict__ Abf,
                                              const ushort_t* __restrict__ Btbf,
                                              const float* __restrict__ bias,
                                              float* __restrict__ out) {
  __shared__ __align__(16) ushort_t As[128 * 32];
  __shared__ __align__(16) ushort_t Bs[128 * 32];
  const int tid = threadIdx.x;
  const int wave = tid >> 6, lane = tid & 63;
  const int wr = wave >> 1, wc = wave & 1;
  const int m15 = lane & 15, quad = lane >> 4;
  const int bm = blockIdx.x, bn = blockIdx.y;
  floatx4 acc[4][4];
#pragma unroll
  for (int i = 0; i < 4; i++)
#pragma unroll
    for (int j = 0; j < 4; j++) acc[i][j] = {0.f, 0.f, 0.f, 0.f};

  const int r0 = tid >> 2, c0 = (tid & 3) * 8;
  const int r1 = r0 + 64;
  for (int k0 = 0; k0 < 512; k0 += 32) {
    *(uint4*)&As[r0 * 32 + c0] = *(const uint4*)&Abf[(size_t)(bm * 128 + r0) * 512 + k0 + c0];
    *(uint4*)&As[r1 * 32 + c0] = *(const uint4*)&Abf[(size_t)(bm * 128 + r1) * 512 + k0 + c0];
    *(uint4*)&Bs[r0 * 32 + c0] = *(const uint4*)&Btbf[(size_t)(bn * 128 + r0) * 512 + k0 + c0];
    *(uint4*)&Bs[r1 * 32 + c0] = *(const uint4*)&Btbf[(size_t)(bn * 128 + r1) * 512 + k0 + c0];
    __syncthreads();
    short8 af[4], bf[4];
#pragma unroll
    for (int i = 0; i < 4; i++)
      af[i] = *(const short8*)&As[(wr * 64 + i * 16 + m15) * 32 + quad * 8];
#pragma unroll
    for (int j = 0; j < 4; j++)
      bf[j] = *(const short8*)&Bs[(wc * 64 + j * 16 + m15) * 32 + quad * 8];
#pragma unroll
    for (int i = 0; i < 4; i++)
#pragma unroll
      for (int j = 0; j < 4; j++)
        acc[i][j] = __builtin_amdgcn_mfma_f32_16x16x32_bf16(af[i], bf[j], acc[i][j], 0, 0, 0);
    __syncthreads();
  }

#pragma unroll
  for (int i = 0; i < 4; i++)
#pragma unroll
    for (int j = 0; j < 4; j++) {
      int col = bn * 128 + wc * 64 + j * 16 + m15;
      float b = bias[col];
#pragma unroll
      for (int r = 0; r < 4; r++) {
        int row = bm * 128 + wr * 64 + i * 16 + quad * 4 + r;
        out[(size_t)row * 512 + col] = acc[i][j][r] + b;
      }
    }
}

extern "C" void kernel_launch(void* const* d_in, const int* in_sizes, int n_in,
                              void* d_out, int out_size, void* d_ws, size_t ws_size,
                              hipStream_t stream) {
  const float* x      = (const float*)d_in[0];
  const float* w_qkv  = (const float*)d_in[1];
  const float* w_proj = (const float*)d_in[2];
  const float* b_proj = (const float*)d_in[3];
  const float* w_off  = (const float*)d_in[4];
  const float* rel_d  = (const float*)d_in[5];
  const float* rel_h  = (const float*)d_in[6];
  const float* rel_w  = (const float*)d_in[7];

  char* ws = (char*)d_ws;
  float*    qb     = (float*)ws;                          ws += (size_t)NH * NTOK * 64 * 4;   // 8 MB
  uint32_t* kvb    = (uint32_t*)ws;                       ws += (size_t)NH * NTOK * 64 * 4;   // 8 MB
  float*    ob     = (float*)ws;                          ws += (size_t)NH * NTOK * 81 * 4;   // 10.6 MB
  float*    Pb     = (float*)ws;                          ws += (size_t)NH * NTOK * 126 * 4;  // 16.5 MB
  ushort_t* attb16 = (ushort_t*)ws;                       ws += (size_t)NTOK * CDIM * 2;      // 4 MB
  ushort_t* xbf    = (ushort_t*)ws;                       ws += (size_t)NTOK * CDIM * 2;      // 4 MB
  ushort_t* wqbf   = (ushort_t*)ws;                       ws += (size_t)3 * CDIM * CDIM * 2;  // 1.5 MB
  ushort_t* wpbf   = (ushort_t*)ws;                       ws += (size_t)CDIM * CDIM * 2;      // 0.5 MB
  float*    out    = (float*)d_out;

  k_cvt <<<dim3(3072), dim3(256), 0, stream>>>((const float4*)x, (const float4*)w_qkv,
                                               (const float4*)w_proj, xbf, wqbf, wpbf);
  k_qkv <<<dim3(32, 12), dim3(256), 0, stream>>>(xbf, wqbf, qb, kvb);
  k_off <<<dim3(4096),  dim3(256), 0, stream>>>(x, w_off, ob);
  k_pos <<<dim3(4096),  dim3(256), 0, stream>>>(qb, rel_d, rel_h, rel_w, Pb);
  k_attn<<<dim3(8192),  dim3(256), 0, stream>>>(qb, kvb, ob, Pb, attb16);
  k_proj<<<dim3(32, 4), dim3(256), 0, stream>>>(attb16, wpbf, b_proj, out);
}

// Round 6
// 290.751 us; speedup vs baseline: 2.8579x; 1.0635x over previous
//
#include <hip/hip_runtime.h>
#include <hip/hip_fp16.h>
#include <math.h>
#include <stdint.h>

#define NH    8
#define HD    64
#define NTOK  4096   // D*H*W = 16^3
#define CDIM  512
#define NSAMP 27

typedef __attribute__((ext_vector_type(8))) _Float16 half8;
typedef __attribute__((ext_vector_type(4))) float floatx4;
typedef unsigned short ushort_t;

__device__ __forceinline__ ushort_t f16b(float f) {
  return __half_as_ushort(__float2half(f));
}

// Full 64-lane sum via DPP (pure VALU, no LDS): result uniform via readlane(63)
__device__ __forceinline__ float wave_sum_bcast(float x) {
#define DPP_STEP(ctrl, rmask)                                                   \
  { int t = __builtin_amdgcn_update_dpp(0, __float_as_int(x), ctrl, rmask, 0xf, \
                                        true);                                  \
    x += __int_as_float(t); }
  DPP_STEP(0x111, 0xf)  // row_shr:1
  DPP_STEP(0x112, 0xf)  // row_shr:2
  DPP_STEP(0x114, 0xf)  // row_shr:4
  DPP_STEP(0x118, 0xf)  // row_shr:8  -> lane15 of each row = row sum
  DPP_STEP(0x142, 0xa)  // row_bcast:15 into rows 1,3
  DPP_STEP(0x143, 0xc)  // row_bcast:31 into rows 2,3 -> lane63 = total
#undef DPP_STEP
  return __int_as_float(__builtin_amdgcn_readlane(__float_as_int(x), 63));
}

// ============ Kernel 0: fp32 -> f16 conversion for x, w_qkv, w_proj ============
__global__ __launch_bounds__(256) void k_cvt(const float4* __restrict__ x,
                                             const float4* __restrict__ wq,
                                             const float4* __restrict__ wp,
                                             ushort_t* __restrict__ xb,
                                             ushort_t* __restrict__ wqb,
                                             ushort_t* __restrict__ wpb) {
  int i = blockIdx.x * 256 + threadIdx.x;   // 0 .. 786431 float4s
  const float4* src; ushort_t* dst; int off;
  if (i < 524288)      { src = x;  dst = xb;  off = i; }
  else if (i < 720896) { src = wq; dst = wqb; off = i - 524288; }
  else                 { src = wp; dst = wpb; off = i - 720896; }
  float4 v = src[off];
  ushort4 o = make_ushort4(f16b(v.x), f16b(v.y), f16b(v.z), f16b(v.w));
  *(ushort4*)&dst[(size_t)off * 4] = o;
}

// ============ Kernel 1: qkv GEMM via MFMA f16 ============
// C(4096x1536) = A(4096x512) @ Bt(1536x512)^T ; epilogue scatters
// q -> fp32 head-major, k/v -> packed f16 halves of kvb dwords.
__global__ __launch_bounds__(256) void k_qkv(const ushort_t* __restrict__ Ah,
                                             const ushort_t* __restrict__ Bth,
                                             float* __restrict__ qb,
                                             uint32_t* __restrict__ kvb) {
  __shared__ __align__(16) ushort_t As[128 * 32];
  __shared__ __align__(16) ushort_t Bs[128 * 32];
  const int tid = threadIdx.x;
  const int wave = tid >> 6, lane = tid & 63;
  const int wr = wave >> 1, wc = wave & 1;
  const int m15 = lane & 15, quad = lane >> 4;
  const int bm = blockIdx.x, bn = blockIdx.y;
  floatx4 acc[4][4];
#pragma unroll
  for (int i = 0; i < 4; i++)
#pragma unroll
    for (int j = 0; j < 4; j++) acc[i][j] = {0.f, 0.f, 0.f, 0.f};

  const int r0 = tid >> 2, c0 = (tid & 3) * 8;
  const int r1 = r0 + 64;
  for (int k0 = 0; k0 < 512; k0 += 32) {
    *(uint4*)&As[r0 * 32 + c0] = *(const uint4*)&Ah[(size_t)(bm * 128 + r0) * 512 + k0 + c0];
    *(uint4*)&As[r1 * 32 + c0] = *(const uint4*)&Ah[(size_t)(bm * 128 + r1) * 512 + k0 + c0];
    *(uint4*)&Bs[r0 * 32 + c0] = *(const uint4*)&Bth[(size_t)(bn * 128 + r0) * 512 + k0 + c0];
    *(uint4*)&Bs[r1 * 32 + c0] = *(const uint4*)&Bth[(size_t)(bn * 128 + r1) * 512 + k0 + c0];
    __syncthreads();
    half8 af[4], bf[4];
#pragma unroll
    for (int i = 0; i < 4; i++)
      af[i] = *(const half8*)&As[(wr * 64 + i * 16 + m15) * 32 + quad * 8];
#pragma unroll
    for (int j = 0; j < 4; j++)
      bf[j] = *(const half8*)&Bs[(wc * 64 + j * 16 + m15) * 32 + quad * 8];
#pragma unroll
    for (int i = 0; i < 4; i++)
#pragma unroll
      for (int j = 0; j < 4; j++)
        acc[i][j] = __builtin_amdgcn_mfma_f32_16x16x32_f16(af[i], bf[j], acc[i][j], 0, 0, 0);
    __syncthreads();
  }

  ushort_t* kvh16 = (ushort_t*)kvb;
#pragma unroll
  for (int i = 0; i < 4; i++)
#pragma unroll
    for (int j = 0; j < 4; j++) {
      int col = bn * 128 + wc * 64 + j * 16 + m15;
      int t = col >> 9;          // 0:q 1:k 2:v
      int h = (col >> 6) & 7;
      int d = col & 63;
#pragma unroll
      for (int r = 0; r < 4; r++) {
        int row = bm * 128 + wr * 64 + i * 16 + quad * 4 + r;
        size_t idx = ((size_t)h * NTOK + row) * 64 + d;
        float v = acc[i][j][r];
        if (t == 0) qb[idx] = v;
        else kvh16[idx * 2 + (t - 1)] = f16b(v);   // k -> low, v -> high half
      }
    }
}

// ============ Kernel 2: offsets obuf[h][n][j] = x_chunk(n,h) . w_off[j] ============
__global__ __launch_bounds__(256) void k_off(const float* __restrict__ x,
                                             const float* __restrict__ w_off,
                                             float* __restrict__ obuf) {
  __shared__ float xs[512];
  __shared__ float wsT[64][81];
  const int n = blockIdx.x;
  const int tid = threadIdx.x;
  xs[tid] = x[(size_t)n * 512 + tid];
  xs[tid + 256] = x[(size_t)n * 512 + tid + 256];
  for (int t = tid; t < 81 * 64; t += 256) {
    int j = t >> 6, d = t & 63;
    wsT[d][j] = w_off[t];
  }
  __syncthreads();
  for (int m = tid; m < NH * 81; m += 256) {
    int h = m / 81, j = m - h * 81;
    float acc = 0.f;
#pragma unroll
    for (int d = 0; d < 64; d++) acc += xs[h * 64 + d] * wsT[d][j];
    obuf[((size_t)h * NTOK + n) * 81 + j] = acc;
  }
}

// ============ Kernel 3: P[h][n][j] = q . concat(rel_w, rel_h, rel_d)[j] ============
__global__ __launch_bounds__(256) void k_pos(const float* __restrict__ qb,
                                             const float* __restrict__ rel_d,
                                             const float* __restrict__ rel_h,
                                             const float* __restrict__ rel_w,
                                             float* __restrict__ Pbuf) {
  __shared__ float qs[512];
  __shared__ float relT[64][128];
  const int n = blockIdx.x;
  const int tid = threadIdx.x;
  {
    int h = tid >> 6, d = tid & 63;
    qs[tid] = qb[((size_t)h * NTOK + n) * 64 + d];
    int h2 = (tid + 256) >> 6;
    qs[tid + 256] = qb[((size_t)h2 * NTOK + n) * 64 + d];
  }
  for (int t = tid; t < 42 * 64; t += 256) {
    int j = t >> 6, d = t & 63;
    relT[d][j]      = rel_w[t];
    relT[d][42 + j] = rel_h[t];
    relT[d][84 + j] = rel_d[t];
  }
  __syncthreads();
  for (int m = tid; m < NH * 126; m += 256) {
    int h = m / 126, j = m - h * 126;
    float acc = 0.f;
#pragma unroll
    for (int d = 0; d < 64; d++) acc += qs[h * 64 + d] * relT[d][j];
    Pbuf[((size_t)h * NTOK + n) * 126 + j] = acc;
  }
}

// ============ Kernel 4: fused deformable attention (one wave per (h,n)) ============
// R6: f16 packed k/v, byte offsets (1 v_add per corner), f16 vpair packing.
__global__ __launch_bounds__(256) void k_attn(const float* __restrict__ qb,
                                              const uint32_t* __restrict__ kvb,
                                              const float* __restrict__ obuf,
                                              const float* __restrict__ Pbuf,
                                              ushort_t* __restrict__ attb16) {
  __shared__ int      s_off[4][NSAMP][8];   // BYTE offsets (voxel*256)
  __shared__ float    s_cw[4][NSAMP][8];
  __shared__ uint32_t vpair[4][14][64];     // half2(v[2p], v[2p+1]) per channel
  __shared__ float    s_w[4][28];
  const int bid = blockIdx.x;
  const int h = bid & 7;
  const int wave = threadIdx.x >> 6;
  const int lane = threadIdx.x & 63;
  const int n = (bid >> 3) * 4 + wave;
  const int z = n >> 8, y = (n >> 4) & 15, xq = n & 15;
  const float qd = qb[((size_t)h * NTOK + n) * 64 + lane];
  const char* kvc = (const char*)(kvb + (size_t)h * NTOK * 64);
  const uint32_t lane4 = (uint32_t)lane * 4u;

  if (lane < NSAMP) {
    const int s = lane;
    const float* op = &obuf[((size_t)h * NTOK + n) * 81 + s * 3];
    float oz = op[0], oy = op[1], ox = op[2];
    float pz = (float)(z + (s / 9) - 1) + oz;
    float py = (float)(y + ((s / 3) % 3) - 1) + oy;
    float px = (float)(xq + (s % 3) - 1) + ox;
    float fz = floorf(pz), fy = floorf(py), fx = floorf(px);
    float wz = pz - fz, wy = py - fy, wx = px - fx;
    int z0 = (int)fz, y0 = (int)fy, x0 = (int)fx;
    int   oarr[8];
    float warr[8];
#pragma unroll
    for (int c = 0; c < 8; c++) {
      int dz = (c >> 2) & 1, dy = (c >> 1) & 1, dx = c & 1;
      int zi = z0 + dz, yi = y0 + dy, xi = x0 + dx;
      bool valid = (zi >= 0) && (zi < 16) && (yi >= 0) && (yi < 16) && (xi >= 0) && (xi < 16);
      float w = (dz ? wz : 1.f - wz) * (dy ? wy : 1.f - wy) * (dx ? wx : 1.f - wx);
      int zc = min(max(zi, 0), 15), yc = min(max(yi, 0), 15), xc = min(max(xi, 0), 15);
      oarr[c] = ((zc * 16 + yc) * 16 + xc) * 256;   // byte offset of voxel row
      warr[c] = valid ? w : 0.f;
    }
    *(int4*)&s_off[wave][s][0]   = make_int4(oarr[0], oarr[1], oarr[2], oarr[3]);
    *(int4*)&s_off[wave][s][4]   = make_int4(oarr[4], oarr[5], oarr[6], oarr[7]);
    *(float4*)&s_cw[wave][s][0]  = make_float4(warr[0], warr[1], warr[2], warr[3]);
    *(float4*)&s_cw[wave][s][4]  = make_float4(warr[4], warr[5], warr[6], warr[7]);
  }
  // no __syncthreads: producers/consumers are the same wave (in-order ds)

  float mydot = 0.f;
  float av_even = 0.f;
#pragma unroll 2
  for (int s = 0; s < NSAMP; s++) {
    int4   o0 = *(const int4*)&s_off[wave][s][0];
    int4   o1 = *(const int4*)&s_off[wave][s][4];
    float4 w0 = *(const float4*)&s_cw[wave][s][0];
    float4 w1 = *(const float4*)&s_cw[wave][s][4];
    float ak = 0.f, av = 0.f;
    uint32_t p;
#define CORNER(OV, WV)                                                       \
    p = *(const uint32_t*)(kvc + (uint32_t)((uint32_t)OV + lane4));          \
    { __half2 ph = __builtin_bit_cast(__half2, p);                           \
      ak = fmaf(WV, __half2float(ph.x), ak);                                 \
      av = fmaf(WV, __half2float(ph.y), av); }
    CORNER(o0.x, w0.x) CORNER(o0.y, w0.y) CORNER(o0.z, w0.z) CORNER(o0.w, w0.w)
    CORNER(o1.x, w1.x) CORNER(o1.y, w1.y) CORNER(o1.z, w1.z) CORNER(o1.w, w1.w)
#undef CORNER
    float tot = wave_sum_bcast(qd * ak);   // uniform (SGPR)
    mydot = (lane == s) ? tot : mydot;
    if (s & 1) {
      __half2 hp;
      hp.x = __float2half(av_even);
      hp.y = __float2half(av);
      vpair[wave][s >> 1][lane] = __builtin_bit_cast(uint32_t, hp);
    } else {
      av_even = av;
    }
  }
  {
    __half2 hp;
    hp.x = __float2half(av_even);
    hp.y = __float2half(0.f);
    vpair[wave][13][lane] = __builtin_bit_cast(uint32_t, hp);
  }

  float logit = -INFINITY;
  if (lane < NSAMP) {
    int j = 15 + lane - xq;
    int n2 = (z * 16 + xq) * 16 + y;
    int n3 = (xq * 16 + z) * 16 + y;
    float pos = Pbuf[((size_t)h * NTOK + n) * 126 + j]
              + Pbuf[((size_t)h * NTOK + n2) * 126 + 42 + j]
              + Pbuf[((size_t)h * NTOK + n3) * 126 + 84 + j];
    logit = mydot * 0.125f + pos;
  }

  float mx = logit;
#pragma unroll
  for (int off = 32; off >= 1; off >>= 1) mx = fmaxf(mx, __shfl_xor(mx, off, 64));
  float e = __expf(logit - mx);
  float sum = e;
#pragma unroll
  for (int off = 32; off >= 1; off >>= 1) sum += __shfl_xor(sum, off, 64);
  const float inv = 1.f / sum;
  if (lane < 28) s_w[wave][lane] = e * inv;

  float out = 0.f;
#pragma unroll
  for (int p2 = 0; p2 < 14; p2++) {
    __half2 hv = __builtin_bit_cast(__half2, vpair[wave][p2][lane]);
    float2 wp = *(const float2*)&s_w[wave][2 * p2];
    out = fmaf(wp.x, __half2float(hv.x), out);
    out = fmaf(wp.y, __half2float(hv.y), out);
  }
  attb16[(size_t)n * 512 + h * 64 + lane] = f16b(out);
}

// ============ Kernel 5: proj GEMM via MFMA f16: out = attb @ w_proj^T + b ============
__global__ __launch_bounds__(256) void k_proj(const ushort_t* __restrict__ Ah,
                                              const ushort_t* __restrict__ Bth,
                                              const float* __restrict__ bias,
                                              float* __restrict__ out) {
  __shared__ __align__(16) ushort_t As[128 * 32];
  __shared__ __align__(16) ushort_t Bs[128 * 32];
  const int tid = threadIdx.x;
  const int wave = tid >> 6, lane = tid & 63;
  const int wr = wave >> 1, wc = wave & 1;
  const int m15 = lane & 15, quad = lane >> 4;
  const int bm = blockIdx.x, bn = blockIdx.y;
  floatx4 acc[4][4];
#pragma unroll
  for (int i = 0; i < 4; i++)
#pragma unroll
    for (int j = 0; j < 4; j++) acc[i][j] = {0.f, 0.f, 0.f, 0.f};

  const int r0 = tid >> 2, c0 = (tid & 3) * 8;
  const int r1 = r0 + 64;
  for (int k0 = 0; k0 < 512; k0 += 32) {
    *(uint4*)&As[r0 * 32 + c0] = *(const uint4*)&Ah[(size_t)(bm * 128 + r0) * 512 + k0 + c0];
    *(uint4*)&As[r1 * 32 + c0] = *(const uint4*)&Ah[(size_t)(bm * 128 + r1) * 512 + k0 + c0];
    *(uint4*)&Bs[r0 * 32 + c0] = *(const uint4*)&Bth[(size_t)(bn * 128 + r0) * 512 + k0 + c0];
    *(uint4*)&Bs[r1 * 32 + c0] = *(const uint4*)&Bth[(size_t)(bn * 128 + r1) * 512 + k0 + c0];
    __syncthreads();
    half8 af[4], bf[4];
#pragma unroll
    for (int i = 0; i < 4; i++)
      af[i] = *(const half8*)&As[(wr * 64 + i * 16 + m15) * 32 + quad * 8];
#pragma unroll
    for (int j = 0; j < 4; j++)
      bf[j] = *(const half8*)&Bs[(wc * 64 + j * 16 + m15) * 32 + quad * 8];
#pragma unroll
    for (int i = 0; i < 4; i++)
#pragma unroll
      for (int j = 0; j < 4; j++)
        acc[i][j] = __builtin_amdgcn_mfma_f32_16x16x32_f16(af[i], bf[j], acc[i][j], 0, 0, 0);
    __syncthreads();
  }

#pragma unroll
  for (int i = 0; i < 4; i++)
#pragma unroll
    for (int j = 0; j < 4; j++) {
      int col = bn * 128 + wc * 64 + j * 16 + m15;
      float b = bias[col];
#pragma unroll
      for (int r = 0; r < 4; r++) {
        int row = bm * 128 + wr * 64 + i * 16 + quad * 4 + r;
        out[(size_t)row * 512 + col] = acc[i][j][r] + b;
      }
    }
}

extern "C" void kernel_launch(void* const* d_in, const int* in_sizes, int n_in,
                              void* d_out, int out_size, void* d_ws, size_t ws_size,
                              hipStream_t stream) {
  const float* x      = (const float*)d_in[0];
  const float* w_qkv  = (const float*)d_in[1];
  const float* w_proj = (const float*)d_in[2];
  const float* b_proj = (const float*)d_in[3];
  const float* w_off  = (const float*)d_in[4];
  const float* rel_d  = (const float*)d_in[5];
  const float* rel_h  = (const float*)d_in[6];
  const float* rel_w  = (const float*)d_in[7];

  char* ws = (char*)d_ws;
  float*    qb     = (float*)ws;    ws += (size_t)NH * NTOK * 64 * 4;
  uint32_t* kvb    = (uint32_t*)ws; ws += (size_t)NH * NTOK * 64 * 4;
  float*    ob     = (float*)ws;    ws += (size_t)NH * NTOK * 81 * 4;
  float*    Pb     = (float*)ws;    ws += (size_t)NH * NTOK * 126 * 4;
  ushort_t* attb16 = (ushort_t*)ws; ws += (size_t)NTOK * CDIM * 2;
  ushort_t* xh     = (ushort_t*)ws; ws += (size_t)NTOK * CDIM * 2;
  ushort_t* wqh    = (ushort_t*)ws; ws += (size_t)3 * CDIM * CDIM * 2;
  ushort_t* wph    = (ushort_t*)ws; ws += (size_t)CDIM * CDIM * 2;
  float*    out    = (float*)d_out;

  k_cvt <<<dim3(3072), dim3(256), 0, stream>>>((const float4*)x, (const float4*)w_qkv,
                                               (const float4*)w_proj, xh, wqh, wph);
  k_qkv <<<dim3(32, 12), dim3(256), 0, stream>>>(xh, wqh, qb, kvb);
  k_off <<<dim3(4096),  dim3(256), 0, stream>>>(x, w_off, ob);
  k_pos <<<dim3(4096),  dim3(256), 0, stream>>>(qb, rel_d, rel_h, rel_w, Pb);
  k_attn<<<dim3(8192),  dim3(256), 0, stream>>>(qb, kvb, ob, Pb, attb16);
  k_proj<<<dim3(32, 4), dim3(256), 0, stream>>>(attb16, wph, b_proj, out);
}

// Round 7
// 197.378 us; speedup vs baseline: 4.2099x; 1.4731x over previous
//
#include <hip/hip_runtime.h>
#include <hip/hip_fp16.h>
#include <math.h>
#include <stdint.h>

#define NH    8
#define HD    64
#define NTOK  4096   // D*H*W = 16^3
#define CDIM  512
#define NSAMP 27

typedef __attribute__((ext_vector_type(8))) _Float16 half8;
typedef __attribute__((ext_vector_type(4))) float floatx4;
typedef unsigned short ushort_t;

__device__ __forceinline__ ushort_t f16b(float f) {
  return __half_as_ushort(__float2half(f));
}

// Full 64-lane sum via DPP (pure VALU, no LDS): result uniform via readlane(63)
__device__ __forceinline__ float wave_sum_bcast(float x) {
#define DPP_STEP(ctrl, rmask)                                                   \
  { int t = __builtin_amdgcn_update_dpp(0, __float_as_int(x), ctrl, rmask, 0xf, \
                                        true);                                  \
    x += __int_as_float(t); }
  DPP_STEP(0x111, 0xf)  // row_shr:1
  DPP_STEP(0x112, 0xf)  // row_shr:2
  DPP_STEP(0x114, 0xf)  // row_shr:4
  DPP_STEP(0x118, 0xf)  // row_shr:8  -> lane15 of each row = row sum
  DPP_STEP(0x142, 0xa)  // row_bcast:15 into rows 1,3
  DPP_STEP(0x143, 0xc)  // row_bcast:31 into rows 2,3 -> lane63 = total
#undef DPP_STEP
  return __int_as_float(__builtin_amdgcn_readlane(__float_as_int(x), 63));
}

// ============ Kernel 0a: fp32 -> f16 conversion for x, w_qkv, w_proj ============
__global__ __launch_bounds__(256) void k_cvt(const float4* __restrict__ x,
                                             const float4* __restrict__ wq,
                                             const float4* __restrict__ wp,
                                             ushort_t* __restrict__ xb,
                                             ushort_t* __restrict__ wqb,
                                             ushort_t* __restrict__ wpb) {
  int i = blockIdx.x * 256 + threadIdx.x;   // 0 .. 786431 float4s
  const float4* src; ushort_t* dst; int off;
  if (i < 524288)      { src = x;  dst = xb;  off = i; }
  else if (i < 720896) { src = wq; dst = wqb; off = i - 524288; }
  else                 { src = wp; dst = wpb; off = i - 720896; }
  float4 v = src[off];
  ushort4 o = make_ushort4(f16b(v.x), f16b(v.y), f16b(v.z), f16b(v.w));
  *(ushort4*)&dst[(size_t)off * 4] = o;
}

// ============ Kernel 0b: pack w_off -> [128][64] f16, concat(rel_w,h,d) -> [128][64] f16 ============
__global__ __launch_bounds__(256) void k_cvt2(const float* __restrict__ w_off,
                                              const float* __restrict__ rel_d,
                                              const float* __restrict__ rel_h,
                                              const float* __restrict__ rel_w,
                                              ushort_t* __restrict__ w_offh,
                                              ushort_t* __restrict__ relh) {
  int i = blockIdx.x * 256 + threadIdx.x;   // 0..16383
  int row = (i & 8191) >> 6, d = i & 63;
  if (i < 8192) {
    float v = (row < 81) ? w_off[row * 64 + d] : 0.f;
    w_offh[row * 64 + d] = f16b(v);
  } else {
    float v;
    if (row < 42)       v = rel_w[row * 64 + d];
    else if (row < 84)  v = rel_h[(row - 42) * 64 + d];
    else if (row < 126) v = rel_d[(row - 84) * 64 + d];
    else                v = 0.f;
    relh[row * 64 + d] = f16b(v);
  }
}

// ============ Kernel 1: qkv GEMM via MFMA f16 ============
// q -> fp32 + f16 head-major, k/v -> packed f16 halves of kvb dwords.
__global__ __launch_bounds__(256) void k_qkv(const ushort_t* __restrict__ Ah,
                                             const ushort_t* __restrict__ Bth,
                                             float* __restrict__ qb,
                                             ushort_t* __restrict__ qh16,
                                             uint32_t* __restrict__ kvb) {
  __shared__ __align__(16) ushort_t As[128 * 32];
  __shared__ __align__(16) ushort_t Bs[128 * 32];
  const int tid = threadIdx.x;
  const int wave = tid >> 6, lane = tid & 63;
  const int wr = wave >> 1, wc = wave & 1;
  const int m15 = lane & 15, quad = lane >> 4;
  const int bm = blockIdx.x, bn = blockIdx.y;
  floatx4 acc[4][4];
#pragma unroll
  for (int i = 0; i < 4; i++)
#pragma unroll
    for (int j = 0; j < 4; j++) acc[i][j] = {0.f, 0.f, 0.f, 0.f};

  const int r0 = tid >> 2, c0 = (tid & 3) * 8;
  const int r1 = r0 + 64;
  for (int k0 = 0; k0 < 512; k0 += 32) {
    *(uint4*)&As[r0 * 32 + c0] = *(const uint4*)&Ah[(size_t)(bm * 128 + r0) * 512 + k0 + c0];
    *(uint4*)&As[r1 * 32 + c0] = *(const uint4*)&Ah[(size_t)(bm * 128 + r1) * 512 + k0 + c0];
    *(uint4*)&Bs[r0 * 32 + c0] = *(const uint4*)&Bth[(size_t)(bn * 128 + r0) * 512 + k0 + c0];
    *(uint4*)&Bs[r1 * 32 + c0] = *(const uint4*)&Bth[(size_t)(bn * 128 + r1) * 512 + k0 + c0];
    __syncthreads();
    half8 af[4], bf[4];
#pragma unroll
    for (int i = 0; i < 4; i++)
      af[i] = *(const half8*)&As[(wr * 64 + i * 16 + m15) * 32 + quad * 8];
#pragma unroll
    for (int j = 0; j < 4; j++)
      bf[j] = *(const half8*)&Bs[(wc * 64 + j * 16 + m15) * 32 + quad * 8];
#pragma unroll
    for (int i = 0; i < 4; i++)
#pragma unroll
      for (int j = 0; j < 4; j++)
        acc[i][j] = __builtin_amdgcn_mfma_f32_16x16x32_f16(af[i], bf[j], acc[i][j], 0, 0, 0);
    __syncthreads();
  }

  ushort_t* kvh16 = (ushort_t*)kvb;
#pragma unroll
  for (int i = 0; i < 4; i++)
#pragma unroll
    for (int j = 0; j < 4; j++) {
      int col = bn * 128 + wc * 64 + j * 16 + m15;
      int t = col >> 9;          // 0:q 1:k 2:v
      int h = (col >> 6) & 7;
      int d = col & 63;
#pragma unroll
      for (int r = 0; r < 4; r++) {
        int row = bm * 128 + wr * 64 + i * 16 + quad * 4 + r;
        size_t idx = ((size_t)h * NTOK + row) * 64 + d;
        float v = acc[i][j][r];
        if (t == 0) { qb[idx] = v; qh16[idx] = f16b(v); }
        else kvh16[idx * 2 + (t - 1)] = f16b(v);   // k -> low, v -> high half
      }
    }
}

// ============ Kernel 2: offsets via MFMA: ob_h = x[:, h*64:h*64+64] @ w_off^T ============
__global__ __launch_bounds__(256) void k_offmm(const ushort_t* __restrict__ xh,
                                               const ushort_t* __restrict__ w_offh,  // [128][64]
                                               float* __restrict__ obuf) {
  __shared__ __align__(16) ushort_t As[128 * 32];
  __shared__ __align__(16) ushort_t Bs[128 * 32];
  const int tid = threadIdx.x;
  const int wave = tid >> 6, lane = tid & 63;
  const int wr = wave >> 1, wc = wave & 1;
  const int m15 = lane & 15, quad = lane >> 4;
  const int bm = blockIdx.x, h = blockIdx.y;
  floatx4 acc[4][4];
#pragma unroll
  for (int i = 0; i < 4; i++)
#pragma unroll
    for (int j = 0; j < 4; j++) acc[i][j] = {0.f, 0.f, 0.f, 0.f};

  const int r0 = tid >> 2, c0 = (tid & 3) * 8;
  const int r1 = r0 + 64;
  for (int k0 = 0; k0 < 64; k0 += 32) {
    *(uint4*)&As[r0 * 32 + c0] = *(const uint4*)&xh[(size_t)(bm * 128 + r0) * 512 + h * 64 + k0 + c0];
    *(uint4*)&As[r1 * 32 + c0] = *(const uint4*)&xh[(size_t)(bm * 128 + r1) * 512 + h * 64 + k0 + c0];
    *(uint4*)&Bs[r0 * 32 + c0] = *(const uint4*)&w_offh[(size_t)r0 * 64 + k0 + c0];
    *(uint4*)&Bs[r1 * 32 + c0] = *(const uint4*)&w_offh[(size_t)r1 * 64 + k0 + c0];
    __syncthreads();
    half8 af[4], bf[4];
#pragma unroll
    for (int i = 0; i < 4; i++)
      af[i] = *(const half8*)&As[(wr * 64 + i * 16 + m15) * 32 + quad * 8];
#pragma unroll
    for (int j = 0; j < 4; j++)
      bf[j] = *(const half8*)&Bs[(wc * 64 + j * 16 + m15) * 32 + quad * 8];
#pragma unroll
    for (int i = 0; i < 4; i++)
#pragma unroll
      for (int j = 0; j < 4; j++)
        acc[i][j] = __builtin_amdgcn_mfma_f32_16x16x32_f16(af[i], bf[j], acc[i][j], 0, 0, 0);
    __syncthreads();
  }

#pragma unroll
  for (int i = 0; i < 4; i++)
#pragma unroll
    for (int j = 0; j < 4; j++) {
      int col = wc * 64 + j * 16 + m15;
      if (col < 81) {
#pragma unroll
        for (int r = 0; r < 4; r++) {
          int row = bm * 128 + wr * 64 + i * 16 + quad * 4 + r;
          obuf[((size_t)h * NTOK + row) * 81 + col] = acc[i][j][r];
        }
      }
    }
}

// ============ Kernel 3: pos via MFMA: P_h = q_h @ concat(rel_w,rel_h,rel_d)^T ============
__global__ __launch_bounds__(256) void k_posmm(const ushort_t* __restrict__ qh16,
                                               const ushort_t* __restrict__ relh,  // [128][64]
                                               float* __restrict__ Pbuf) {
  __shared__ __align__(16) ushort_t As[128 * 32];
  __shared__ __align__(16) ushort_t Bs[128 * 32];
  const int tid = threadIdx.x;
  const int wave = tid >> 6, lane = tid & 63;
  const int wr = wave >> 1, wc = wave & 1;
  const int m15 = lane & 15, quad = lane >> 4;
  const int bm = blockIdx.x, h = blockIdx.y;
  const ushort_t* Ah = qh16 + (size_t)h * NTOK * 64;
  floatx4 acc[4][4];
#pragma unroll
  for (int i = 0; i < 4; i++)
#pragma unroll
    for (int j = 0; j < 4; j++) acc[i][j] = {0.f, 0.f, 0.f, 0.f};

  const int r0 = tid >> 2, c0 = (tid & 3) * 8;
  const int r1 = r0 + 64;
  for (int k0 = 0; k0 < 64; k0 += 32) {
    *(uint4*)&As[r0 * 32 + c0] = *(const uint4*)&Ah[(size_t)(bm * 128 + r0) * 64 + k0 + c0];
    *(uint4*)&As[r1 * 32 + c0] = *(const uint4*)&Ah[(size_t)(bm * 128 + r1) * 64 + k0 + c0];
    *(uint4*)&Bs[r0 * 32 + c0] = *(const uint4*)&relh[(size_t)r0 * 64 + k0 + c0];
    *(uint4*)&Bs[r1 * 32 + c0] = *(const uint4*)&relh[(size_t)r1 * 64 + k0 + c0];
    __syncthreads();
    half8 af[4], bf[4];
#pragma unroll
    for (int i = 0; i < 4; i++)
      af[i] = *(const half8*)&As[(wr * 64 + i * 16 + m15) * 32 + quad * 8];
#pragma unroll
    for (int j = 0; j < 4; j++)
      bf[j] = *(const half8*)&Bs[(wc * 64 + j * 16 + m15) * 32 + quad * 8];
#pragma unroll
    for (int i = 0; i < 4; i++)
#pragma unroll
      for (int j = 0; j < 4; j++)
        acc[i][j] = __builtin_amdgcn_mfma_f32_16x16x32_f16(af[i], bf[j], acc[i][j], 0, 0, 0);
    __syncthreads();
  }

#pragma unroll
  for (int i = 0; i < 4; i++)
#pragma unroll
    for (int j = 0; j < 4; j++) {
      int col = wc * 64 + j * 16 + m15;
      if (col < 126) {
#pragma unroll
        for (int r = 0; r < 4; r++) {
          int row = bm * 128 + wr * 64 + i * 16 + quad * 4 + r;
          Pbuf[((size_t)h * NTOK + row) * 126 + col] = acc[i][j][r];
        }
      }
    }
}

// ============ Kernel 4: fused deformable attention (one wave per (h,n)) ============
__global__ __launch_bounds__(256) void k_attn(const float* __restrict__ qb,
                                              const uint32_t* __restrict__ kvb,
                                              const float* __restrict__ obuf,
                                              const float* __restrict__ Pbuf,
                                              ushort_t* __restrict__ attb16) {
  __shared__ int      s_off[4][NSAMP][8];   // BYTE offsets (voxel*256)
  __shared__ float    s_cw[4][NSAMP][8];
  __shared__ uint32_t vpair[4][14][64];     // half2(v[2p], v[2p+1]) per channel
  __shared__ float    s_w[4][28];
  const int bid = blockIdx.x;
  const int h = bid & 7;
  const int wave = threadIdx.x >> 6;
  const int lane = threadIdx.x & 63;
  const int n = (bid >> 3) * 4 + wave;
  const int z = n >> 8, y = (n >> 4) & 15, xq = n & 15;
  const float qd = qb[((size_t)h * NTOK + n) * 64 + lane];
  const char* kvc = (const char*)(kvb + (size_t)h * NTOK * 64);
  const uint32_t lane4 = (uint32_t)lane * 4u;

  if (lane < NSAMP) {
    const int s = lane;
    const float* op = &obuf[((size_t)h * NTOK + n) * 81 + s * 3];
    float oz = op[0], oy = op[1], ox = op[2];
    float pz = (float)(z + (s / 9) - 1) + oz;
    float py = (float)(y + ((s / 3) % 3) - 1) + oy;
    float px = (float)(xq + (s % 3) - 1) + ox;
    float fz = floorf(pz), fy = floorf(py), fx = floorf(px);
    float wz = pz - fz, wy = py - fy, wx = px - fx;
    int z0 = (int)fz, y0 = (int)fy, x0 = (int)fx;
    int   oarr[8];
    float warr[8];
#pragma unroll
    for (int c = 0; c < 8; c++) {
      int dz = (c >> 2) & 1, dy = (c >> 1) & 1, dx = c & 1;
      int zi = z0 + dz, yi = y0 + dy, xi = x0 + dx;
      bool valid = (zi >= 0) && (zi < 16) && (yi >= 0) && (yi < 16) && (xi >= 0) && (xi < 16);
      float w = (dz ? wz : 1.f - wz) * (dy ? wy : 1.f - wy) * (dx ? wx : 1.f - wx);
      int zc = min(max(zi, 0), 15), yc = min(max(yi, 0), 15), xc = min(max(xi, 0), 15);
      oarr[c] = ((zc * 16 + yc) * 16 + xc) * 256;   // byte offset of voxel row
      warr[c] = valid ? w : 0.f;
    }
    *(int4*)&s_off[wave][s][0]   = make_int4(oarr[0], oarr[1], oarr[2], oarr[3]);
    *(int4*)&s_off[wave][s][4]   = make_int4(oarr[4], oarr[5], oarr[6], oarr[7]);
    *(float4*)&s_cw[wave][s][0]  = make_float4(warr[0], warr[1], warr[2], warr[3]);
    *(float4*)&s_cw[wave][s][4]  = make_float4(warr[4], warr[5], warr[6], warr[7]);
  }
  // no __syncthreads: producers/consumers are the same wave (in-order ds)

  float mydot = 0.f;
  float av_even = 0.f;
#pragma unroll 2
  for (int s = 0; s < NSAMP; s++) {
    int4   o0 = *(const int4*)&s_off[wave][s][0];
    int4   o1 = *(const int4*)&s_off[wave][s][4];
    float4 w0 = *(const float4*)&s_cw[wave][s][0];
    float4 w1 = *(const float4*)&s_cw[wave][s][4];
    float ak = 0.f, av = 0.f;
    uint32_t p;
#define CORNER(OV, WV)                                                       \
    p = *(const uint32_t*)(kvc + (uint32_t)((uint32_t)OV + lane4));          \
    { __half2 ph = __builtin_bit_cast(__half2, p);                           \
      ak = fmaf(WV, __half2float(ph.x), ak);                                 \
      av = fmaf(WV, __half2float(ph.y), av); }
    CORNER(o0.x, w0.x) CORNER(o0.y, w0.y) CORNER(o0.z, w0.z) CORNER(o0.w, w0.w)
    CORNER(o1.x, w1.x) CORNER(o1.y, w1.y) CORNER(o1.z, w1.z) CORNER(o1.w, w1.w)
#undef CORNER
    float tot = wave_sum_bcast(qd * ak);   // uniform (SGPR)
    mydot = (lane == s) ? tot : mydot;
    if (s & 1) {
      __half2 hp;
      hp.x = __float2half(av_even);
      hp.y = __float2half(av);
      vpair[wave][s >> 1][lane] = __builtin_bit_cast(uint32_t, hp);
    } else {
      av_even = av;
    }
  }
  {
    __half2 hp;
    hp.x = __float2half(av_even);
    hp.y = __float2half(0.f);
    vpair[wave][13][lane] = __builtin_bit_cast(uint32_t, hp);
  }

  float logit = -INFINITY;
  if (lane < NSAMP) {
    int j = 15 + lane - xq;
    int n2 = (z * 16 + xq) * 16 + y;
    int n3 = (xq * 16 + z) * 16 + y;
    float pos = Pbuf[((size_t)h * NTOK + n) * 126 + j]
              + Pbuf[((size_t)h * NTOK + n2) * 126 + 42 + j]
              + Pbuf[((size_t)h * NTOK + n3) * 126 + 84 + j];
    logit = mydot * 0.125f + pos;
  }

  float mx = logit;
#pragma unroll
  for (int off = 32; off >= 1; off >>= 1) mx = fmaxf(mx, __shfl_xor(mx, off, 64));
  float e = __expf(logit - mx);
  float sum = e;
#pragma unroll
  for (int off = 32; off >= 1; off >>= 1) sum += __shfl_xor(sum, off, 64);
  const float inv = 1.f / sum;
  if (lane < 28) s_w[wave][lane] = e * inv;

  float out = 0.f;
#pragma unroll
  for (int p2 = 0; p2 < 14; p2++) {
    __half2 hv = __builtin_bit_cast(__half2, vpair[wave][p2][lane]);
    float2 wp = *(const float2*)&s_w[wave][2 * p2];
    out = fmaf(wp.x, __half2float(hv.x), out);
    out = fmaf(wp.y, __half2float(hv.y), out);
  }
  attb16[(size_t)n * 512 + h * 64 + lane] = f16b(out);
}

// ============ Kernel 5: proj GEMM via MFMA f16: out = attb @ w_proj^T + b ============
__global__ __launch_bounds__(256) void k_proj(const ushort_t* __restrict__ Ah,
                                              const ushort_t* __restrict__ Bth,
                                              const float* __restrict__ bias,
                                              float* __restrict__ out) {
  __shared__ __align__(16) ushort_t As[128 * 32];
  __shared__ __align__(16) ushort_t Bs[128 * 32];
  const int tid = threadIdx.x;
  const int wave = tid >> 6, lane = tid & 63;
  const int wr = wave >> 1, wc = wave & 1;
  const int m15 = lane & 15, quad = lane >> 4;
  const int bm = blockIdx.x, bn = blockIdx.y;
  floatx4 acc[4][4];
#pragma unroll
  for (int i = 0; i < 4; i++)
#pragma unroll
    for (int j = 0; j < 4; j++) acc[i][j] = {0.f, 0.f, 0.f, 0.f};

  const int r0 = tid >> 2, c0 = (tid & 3) * 8;
  const int r1 = r0 + 64;
  for (int k0 = 0; k0 < 512; k0 += 32) {
    *(uint4*)&As[r0 * 32 + c0] = *(const uint4*)&Ah[(size_t)(bm * 128 + r0) * 512 + k0 + c0];
    *(uint4*)&As[r1 * 32 + c0] = *(const uint4*)&Ah[(size_t)(bm * 128 + r1) * 512 + k0 + c0];
    *(uint4*)&Bs[r0 * 32 + c0] = *(const uint4*)&Bth[(size_t)(bn * 128 + r0) * 512 + k0 + c0];
    *(uint4*)&Bs[r1 * 32 + c0] = *(const uint4*)&Bth[(size_t)(bn * 128 + r1) * 512 + k0 + c0];
    __syncthreads();
    half8 af[4], bf[4];
#pragma unroll
    for (int i = 0; i < 4; i++)
      af[i] = *(const half8*)&As[(wr * 64 + i * 16 + m15) * 32 + quad * 8];
#pragma unroll
    for (int j = 0; j < 4; j++)
      bf[j] = *(const half8*)&Bs[(wc * 64 + j * 16 + m15) * 32 + quad * 8];
#pragma unroll
    for (int i = 0; i < 4; i++)
#pragma unroll
      for (int j = 0; j < 4; j++)
        acc[i][j] = __builtin_amdgcn_mfma_f32_16x16x32_f16(af[i], bf[j], acc[i][j], 0, 0, 0);
    __syncthreads();
  }

#pragma unroll
  for (int i = 0; i < 4; i++)
#pragma unroll
    for (int j = 0; j < 4; j++) {
      int col = bn * 128 + wc * 64 + j * 16 + m15;
      float b = bias[col];
#pragma unroll
      for (int r = 0; r < 4; r++) {
        int row = bm * 128 + wr * 64 + i * 16 + quad * 4 + r;
        out[(size_t)row * 512 + col] = acc[i][j][r] + b;
      }
    }
}

extern "C" void kernel_launch(void* const* d_in, const int* in_sizes, int n_in,
                              void* d_out, int out_size, void* d_ws, size_t ws_size,
                              hipStream_t stream) {
  const float* x      = (const float*)d_in[0];
  const float* w_qkv  = (const float*)d_in[1];
  const float* w_proj = (const float*)d_in[2];
  const float* b_proj = (const float*)d_in[3];
  const float* w_off  = (const float*)d_in[4];
  const float* rel_d  = (const float*)d_in[5];
  const float* rel_h  = (const float*)d_in[6];
  const float* rel_w  = (const float*)d_in[7];

  char* ws = (char*)d_ws;
  float*    qb     = (float*)ws;    ws += (size_t)NH * NTOK * 64 * 4;
  uint32_t* kvb    = (uint32_t*)ws; ws += (size_t)NH * NTOK * 64 * 4;
  float*    ob     = (float*)ws;    ws += (size_t)NH * NTOK * 81 * 4;
  float*    Pb     = (float*)ws;    ws += (size_t)NH * NTOK * 126 * 4;
  ushort_t* attb16 = (ushort_t*)ws; ws += (size_t)NTOK * CDIM * 2;
  ushort_t* xh     = (ushort_t*)ws; ws += (size_t)NTOK * CDIM * 2;
  ushort_t* wqh    = (ushort_t*)ws; ws += (size_t)3 * CDIM * CDIM * 2;
  ushort_t* wph    = (ushort_t*)ws; ws += (size_t)CDIM * CDIM * 2;
  ushort_t* qh16   = (ushort_t*)ws; ws += (size_t)NH * NTOK * 64 * 2;
  ushort_t* w_offh = (ushort_t*)ws; ws += (size_t)128 * 64 * 2;
  ushort_t* relh   = (ushort_t*)ws; ws += (size_t)128 * 64 * 2;
  float*    out    = (float*)d_out;

  k_cvt  <<<dim3(3072), dim3(256), 0, stream>>>((const float4*)x, (const float4*)w_qkv,
                                                (const float4*)w_proj, xh, wqh, wph);
  k_cvt2 <<<dim3(64),   dim3(256), 0, stream>>>(w_off, rel_d, rel_h, rel_w, w_offh, relh);
  k_qkv  <<<dim3(32, 12), dim3(256), 0, stream>>>(xh, wqh, qb, qh16, kvb);
  k_offmm<<<dim3(32, 8),  dim3(256), 0, stream>>>(xh, w_offh, ob);
  k_posmm<<<dim3(32, 8),  dim3(256), 0, stream>>>(qh16, relh, Pb);
  k_attn <<<dim3(8192),   dim3(256), 0, stream>>>(qb, kvb, ob, Pb, attb16);
  k_proj <<<dim3(32, 4),  dim3(256), 0, stream>>>(attb16, wph, b_proj, out);
}

// Round 8
// 188.481 us; speedup vs baseline: 4.4086x; 1.0472x over previous
//
#include <hip/hip_runtime.h>
#include <hip/hip_fp16.h>
#include <math.h>
#include <stdint.h>

#define NH    8
#define HD    64
#define NTOK  4096   // D*H*W = 16^3
#define CDIM  512
#define NSAMP 27

typedef __attribute__((ext_vector_type(8))) _Float16 half8;
typedef __attribute__((ext_vector_type(4))) float floatx4;
typedef unsigned short ushort_t;

__device__ __forceinline__ ushort_t f16b(float f) {
  return __half_as_ushort(__float2half(f));
}
__device__ __forceinline__ __half2 u2h2(uint32_t u) { return __builtin_bit_cast(__half2, u); }
__device__ __forceinline__ uint32_t h22u(__half2 h) { return __builtin_bit_cast(uint32_t, h); }

// Full 64-lane sum via DPP (pure VALU, no LDS): result uniform via readlane(63)
__device__ __forceinline__ float wave_sum_bcast(float x) {
#define DPP_STEP(ctrl, rmask)                                                   \
  { int t = __builtin_amdgcn_update_dpp(0, __float_as_int(x), ctrl, rmask, 0xf, \
                                        true);                                  \
    x += __int_as_float(t); }
  DPP_STEP(0x111, 0xf)  // row_shr:1
  DPP_STEP(0x112, 0xf)  // row_shr:2
  DPP_STEP(0x114, 0xf)  // row_shr:4
  DPP_STEP(0x118, 0xf)  // row_shr:8  -> lane15 of each row = row sum
  DPP_STEP(0x142, 0xa)  // row_bcast:15 into rows 1,3
  DPP_STEP(0x143, 0xc)  // row_bcast:31 into rows 2,3 -> lane63 = total
#undef DPP_STEP
  return __int_as_float(__builtin_amdgcn_readlane(__float_as_int(x), 63));
}

// ============ Kernel 0a: fp32 -> f16 conversion for x, w_qkv, w_proj ============
__global__ __launch_bounds__(256) void k_cvt(const float4* __restrict__ x,
                                             const float4* __restrict__ wq,
                                             const float4* __restrict__ wp,
                                             ushort_t* __restrict__ xb,
                                             ushort_t* __restrict__ wqb,
                                             ushort_t* __restrict__ wpb) {
  int i = blockIdx.x * 256 + threadIdx.x;   // 0 .. 786431 float4s
  const float4* src; ushort_t* dst; int off;
  if (i < 524288)      { src = x;  dst = xb;  off = i; }
  else if (i < 720896) { src = wq; dst = wqb; off = i - 524288; }
  else                 { src = wp; dst = wpb; off = i - 720896; }
  float4 v = src[off];
  ushort4 o = make_ushort4(f16b(v.x), f16b(v.y), f16b(v.z), f16b(v.w));
  *(ushort4*)&dst[(size_t)off * 4] = o;
}

// ============ Kernel 0b: pack w_off -> [128][64] f16, concat(rel_w,h,d) -> [128][64] f16 ============
__global__ __launch_bounds__(256) void k_cvt2(const float* __restrict__ w_off,
                                              const float* __restrict__ rel_d,
                                              const float* __restrict__ rel_h,
                                              const float* __restrict__ rel_w,
                                              ushort_t* __restrict__ w_offh,
                                              ushort_t* __restrict__ relh) {
  int i = blockIdx.x * 256 + threadIdx.x;   // 0..16383
  int row = (i & 8191) >> 6, d = i & 63;
  if (i < 8192) {
    float v = (row < 81) ? w_off[row * 64 + d] : 0.f;
    w_offh[row * 64 + d] = f16b(v);
  } else {
    float v;
    if (row < 42)       v = rel_w[row * 64 + d];
    else if (row < 84)  v = rel_h[(row - 42) * 64 + d];
    else if (row < 126) v = rel_d[(row - 84) * 64 + d];
    else                v = 0.f;
    relh[row * 64 + d] = f16b(v);
  }
}

// ============ Kernel 1: qkv GEMM via MFMA f16 ============
// q -> f16 head-major, k/v -> packed f16 halves of kvb dwords.
__global__ __launch_bounds__(256) void k_qkv(const ushort_t* __restrict__ Ah,
                                             const ushort_t* __restrict__ Bth,
                                             ushort_t* __restrict__ qh16,
                                             uint32_t* __restrict__ kvb) {
  __shared__ __align__(16) ushort_t As[128 * 32];
  __shared__ __align__(16) ushort_t Bs[128 * 32];
  const int tid = threadIdx.x;
  const int wave = tid >> 6, lane = tid & 63;
  const int wr = wave >> 1, wc = wave & 1;
  const int m15 = lane & 15, quad = lane >> 4;
  const int bm = blockIdx.x, bn = blockIdx.y;
  floatx4 acc[4][4];
#pragma unroll
  for (int i = 0; i < 4; i++)
#pragma unroll
    for (int j = 0; j < 4; j++) acc[i][j] = {0.f, 0.f, 0.f, 0.f};

  const int r0 = tid >> 2, c0 = (tid & 3) * 8;
  const int r1 = r0 + 64;
  for (int k0 = 0; k0 < 512; k0 += 32) {
    *(uint4*)&As[r0 * 32 + c0] = *(const uint4*)&Ah[(size_t)(bm * 128 + r0) * 512 + k0 + c0];
    *(uint4*)&As[r1 * 32 + c0] = *(const uint4*)&Ah[(size_t)(bm * 128 + r1) * 512 + k0 + c0];
    *(uint4*)&Bs[r0 * 32 + c0] = *(const uint4*)&Bth[(size_t)(bn * 128 + r0) * 512 + k0 + c0];
    *(uint4*)&Bs[r1 * 32 + c0] = *(const uint4*)&Bth[(size_t)(bn * 128 + r1) * 512 + k0 + c0];
    __syncthreads();
    half8 af[4], bf[4];
#pragma unroll
    for (int i = 0; i < 4; i++)
      af[i] = *(const half8*)&As[(wr * 64 + i * 16 + m15) * 32 + quad * 8];
#pragma unroll
    for (int j = 0; j < 4; j++)
      bf[j] = *(const half8*)&Bs[(wc * 64 + j * 16 + m15) * 32 + quad * 8];
#pragma unroll
    for (int i = 0; i < 4; i++)
#pragma unroll
      for (int j = 0; j < 4; j++)
        acc[i][j] = __builtin_amdgcn_mfma_f32_16x16x32_f16(af[i], bf[j], acc[i][j], 0, 0, 0);
    __syncthreads();
  }

  ushort_t* kvh16 = (ushort_t*)kvb;
#pragma unroll
  for (int i = 0; i < 4; i++)
#pragma unroll
    for (int j = 0; j < 4; j++) {
      int col = bn * 128 + wc * 64 + j * 16 + m15;
      int t = col >> 9;          // 0:q 1:k 2:v
      int h = (col >> 6) & 7;
      int d = col & 63;
#pragma unroll
      for (int r = 0; r < 4; r++) {
        int row = bm * 128 + wr * 64 + i * 16 + quad * 4 + r;
        size_t idx = ((size_t)h * NTOK + row) * 64 + d;
        float v = acc[i][j][r];
        if (t == 0) qh16[idx] = f16b(v);
        else kvh16[idx * 2 + (t - 1)] = f16b(v);   // k -> low, v -> high half
      }
    }
}

// ============ Kernel 2: offsets via MFMA: ob_h = x[:, h*64:h*64+64] @ w_off^T ============
__global__ __launch_bounds__(256) void k_offmm(const ushort_t* __restrict__ xh,
                                               const ushort_t* __restrict__ w_offh,  // [128][64]
                                               float* __restrict__ obuf) {
  __shared__ __align__(16) ushort_t As[128 * 32];
  __shared__ __align__(16) ushort_t Bs[128 * 32];
  const int tid = threadIdx.x;
  const int wave = tid >> 6, lane = tid & 63;
  const int wr = wave >> 1, wc = wave & 1;
  const int m15 = lane & 15, quad = lane >> 4;
  const int bm = blockIdx.x, h = blockIdx.y;
  floatx4 acc[4][4];
#pragma unroll
  for (int i = 0; i < 4; i++)
#pragma unroll
    for (int j = 0; j < 4; j++) acc[i][j] = {0.f, 0.f, 0.f, 0.f};

  const int r0 = tid >> 2, c0 = (tid & 3) * 8;
  const int r1 = r0 + 64;
  for (int k0 = 0; k0 < 64; k0 += 32) {
    *(uint4*)&As[r0 * 32 + c0] = *(const uint4*)&xh[(size_t)(bm * 128 + r0) * 512 + h * 64 + k0 + c0];
    *(uint4*)&As[r1 * 32 + c0] = *(const uint4*)&xh[(size_t)(bm * 128 + r1) * 512 + h * 64 + k0 + c0];
    *(uint4*)&Bs[r0 * 32 + c0] = *(const uint4*)&w_offh[(size_t)r0 * 64 + k0 + c0];
    *(uint4*)&Bs[r1 * 32 + c0] = *(const uint4*)&w_offh[(size_t)r1 * 64 + k0 + c0];
    __syncthreads();
    half8 af[4], bf[4];
#pragma unroll
    for (int i = 0; i < 4; i++)
      af[i] = *(const half8*)&As[(wr * 64 + i * 16 + m15) * 32 + quad * 8];
#pragma unroll
    for (int j = 0; j < 4; j++)
      bf[j] = *(const half8*)&Bs[(wc * 64 + j * 16 + m15) * 32 + quad * 8];
#pragma unroll
    for (int i = 0; i < 4; i++)
#pragma unroll
      for (int j = 0; j < 4; j++)
        acc[i][j] = __builtin_amdgcn_mfma_f32_16x16x32_f16(af[i], bf[j], acc[i][j], 0, 0, 0);
    __syncthreads();
  }

#pragma unroll
  for (int i = 0; i < 4; i++)
#pragma unroll
    for (int j = 0; j < 4; j++) {
      int col = wc * 64 + j * 16 + m15;
      if (col < 81) {
#pragma unroll
        for (int r = 0; r < 4; r++) {
          int row = bm * 128 + wr * 64 + i * 16 + quad * 4 + r;
          obuf[((size_t)h * NTOK + row) * 81 + col] = acc[i][j][r];
        }
      }
    }
}

// ============ Kernel 3: pos via MFMA: P_h = q_h @ concat(rel_w,rel_h,rel_d)^T ============
__global__ __launch_bounds__(256) void k_posmm(const ushort_t* __restrict__ qh16,
                                               const ushort_t* __restrict__ relh,  // [128][64]
                                               float* __restrict__ Pbuf) {
  __shared__ __align__(16) ushort_t As[128 * 32];
  __shared__ __align__(16) ushort_t Bs[128 * 32];
  const int tid = threadIdx.x;
  const int wave = tid >> 6, lane = tid & 63;
  const int wr = wave >> 1, wc = wave & 1;
  const int m15 = lane & 15, quad = lane >> 4;
  const int bm = blockIdx.x, h = blockIdx.y;
  const ushort_t* Ah = qh16 + (size_t)h * NTOK * 64;
  floatx4 acc[4][4];
#pragma unroll
  for (int i = 0; i < 4; i++)
#pragma unroll
    for (int j = 0; j < 4; j++) acc[i][j] = {0.f, 0.f, 0.f, 0.f};

  const int r0 = tid >> 2, c0 = (tid & 3) * 8;
  const int r1 = r0 + 64;
  for (int k0 = 0; k0 < 64; k0 += 32) {
    *(uint4*)&As[r0 * 32 + c0] = *(const uint4*)&Ah[(size_t)(bm * 128 + r0) * 64 + k0 + c0];
    *(uint4*)&As[r1 * 32 + c0] = *(const uint4*)&Ah[(size_t)(bm * 128 + r1) * 64 + k0 + c0];
    *(uint4*)&Bs[r0 * 32 + c0] = *(const uint4*)&relh[(size_t)r0 * 64 + k0 + c0];
    *(uint4*)&Bs[r1 * 32 + c0] = *(const uint4*)&relh[(size_t)r1 * 64 + k0 + c0];
    __syncthreads();
    half8 af[4], bf[4];
#pragma unroll
    for (int i = 0; i < 4; i++)
      af[i] = *(const half8*)&As[(wr * 64 + i * 16 + m15) * 32 + quad * 8];
#pragma unroll
    for (int j = 0; j < 4; j++)
      bf[j] = *(const half8*)&Bs[(wc * 64 + j * 16 + m15) * 32 + quad * 8];
#pragma unroll
    for (int i = 0; i < 4; i++)
#pragma unroll
      for (int j = 0; j < 4; j++)
        acc[i][j] = __builtin_amdgcn_mfma_f32_16x16x32_f16(af[i], bf[j], acc[i][j], 0, 0, 0);
    __syncthreads();
  }

#pragma unroll
  for (int i = 0; i < 4; i++)
#pragma unroll
    for (int j = 0; j < 4; j++) {
      int col = wc * 64 + j * 16 + m15;
      if (col < 126) {
#pragma unroll
        for (int r = 0; r < 4; r++) {
          int row = bm * 128 + wr * 64 + i * 16 + quad * 4 + r;
          Pbuf[((size_t)h * NTOK + row) * 126 + col] = acc[i][j][r];
        }
      }
    }
}

// ============ Kernel 4: fused deformable attention (one wave per (h,n)) ============
// R8: packed-f16 math — kv dword IS a half2 (k,v); one v_pk_fma_f16 per corner
// accumulates both k-dot and v-sample with zero unpack/convert ops. Weights
// pre-splatted as half2(w,w) in LDS; softmax weights packed as half2 pairs;
// output pass = 14 pk_fma.
__global__ __launch_bounds__(256) void k_attn(const ushort_t* __restrict__ qh16,
                                              const uint32_t* __restrict__ kvb,
                                              const float* __restrict__ obuf,
                                              const float* __restrict__ Pbuf,
                                              ushort_t* __restrict__ attb16) {
  __shared__ int      s_off[4][NSAMP][8];   // BYTE offsets (voxel*256)
  __shared__ uint32_t s_cwh[4][NSAMP][8];   // half2(w,w) splats
  __shared__ uint32_t vpair[4][14][64];     // half2(v[2p], v[2p+1]) per channel
  __shared__ uint32_t s_wp[4][14];          // half2(w[2p], w[2p+1])
  const int bid = blockIdx.x;
  const int h = bid & 7;
  const int wave = threadIdx.x >> 6;
  const int lane = threadIdx.x & 63;
  const int n = (bid >> 3) * 4 + wave;
  const int z = n >> 8, y = (n >> 4) & 15, xq = n & 15;
  const float qd = __half2float(__ushort_as_half(qh16[((size_t)h * NTOK + n) * 64 + lane]));
  const char* kvc = (const char*)(kvb + (size_t)h * NTOK * 64);
  const uint32_t lane4 = (uint32_t)lane * 4u;

  if (lane < NSAMP) {
    const int s = lane;
    const float* op = &obuf[((size_t)h * NTOK + n) * 81 + s * 3];
    float oz = op[0], oy = op[1], ox = op[2];
    float pz = (float)(z + (s / 9) - 1) + oz;
    float py = (float)(y + ((s / 3) % 3) - 1) + oy;
    float px = (float)(xq + (s % 3) - 1) + ox;
    float fz = floorf(pz), fy = floorf(py), fx = floorf(px);
    float wz = pz - fz, wy = py - fy, wx = px - fx;
    int z0 = (int)fz, y0 = (int)fy, x0 = (int)fx;
    int      oarr[8];
    uint32_t warr[8];
#pragma unroll
    for (int c = 0; c < 8; c++) {
      int dz = (c >> 2) & 1, dy = (c >> 1) & 1, dx = c & 1;
      int zi = z0 + dz, yi = y0 + dy, xi = x0 + dx;
      bool valid = (zi >= 0) && (zi < 16) && (yi >= 0) && (yi < 16) && (xi >= 0) && (xi < 16);
      float w = (dz ? wz : 1.f - wz) * (dy ? wy : 1.f - wy) * (dx ? wx : 1.f - wx);
      int zc = min(max(zi, 0), 15), yc = min(max(yi, 0), 15), xc = min(max(xi, 0), 15);
      oarr[c] = ((zc * 16 + yc) * 16 + xc) * 256;       // byte offset of voxel row
      uint32_t hw = (uint32_t)f16b(valid ? w : 0.f);
      warr[c] = hw | (hw << 16);                        // half2(w, w)
    }
    *(int4*)&s_off[wave][s][0]  = make_int4(oarr[0], oarr[1], oarr[2], oarr[3]);
    *(int4*)&s_off[wave][s][4]  = make_int4(oarr[4], oarr[5], oarr[6], oarr[7]);
    *(uint4*)&s_cwh[wave][s][0] = make_uint4(warr[0], warr[1], warr[2], warr[3]);
    *(uint4*)&s_cwh[wave][s][4] = make_uint4(warr[4], warr[5], warr[6], warr[7]);
  }
  // no __syncthreads: producers/consumers are the same wave (in-order ds)

  float mydot = 0.f;
  uint32_t prev_acc = 0;
#pragma unroll 2
  for (int s = 0; s < NSAMP; s++) {
    int4  o0 = *(const int4*)&s_off[wave][s][0];
    int4  o1 = *(const int4*)&s_off[wave][s][4];
    uint4 c0 = *(const uint4*)&s_cwh[wave][s][0];
    uint4 c1 = *(const uint4*)&s_cwh[wave][s][4];
    __half2 acc2 = u2h2(0u);
    uint32_t p;
#define CORNER(OV, WV)                                                       \
    p = *(const uint32_t*)(kvc + (uint32_t)((uint32_t)OV + lane4));          \
    acc2 = __hfma2(u2h2(WV), u2h2(p), acc2);
    CORNER(o0.x, c0.x) CORNER(o0.y, c0.y) CORNER(o0.z, c0.z) CORNER(o0.w, c0.w)
    CORNER(o1.x, c1.x) CORNER(o1.y, c1.y) CORNER(o1.z, c1.z) CORNER(o1.w, c1.w)
#undef CORNER
    float ak = __half2float(acc2.x);
    float tot = wave_sum_bcast(qd * ak);   // uniform (SGPR)
    mydot = (lane == s) ? tot : mydot;
    uint32_t au = h22u(acc2);
    if (s & 1)
      vpair[wave][s >> 1][lane] = (prev_acc >> 16) | (au & 0xffff0000u);
    else
      prev_acc = au;
  }
  vpair[wave][13][lane] = prev_acc >> 16;   // v[26] in low half, 0 in high

  float logit = -INFINITY;
  if (lane < NSAMP) {
    int j = 15 + lane - xq;
    int n2 = (z * 16 + xq) * 16 + y;
    int n3 = (xq * 16 + z) * 16 + y;
    float pos = Pbuf[((size_t)h * NTOK + n) * 126 + j]
              + Pbuf[((size_t)h * NTOK + n2) * 126 + 42 + j]
              + Pbuf[((size_t)h * NTOK + n3) * 126 + 84 + j];
    logit = mydot * 0.125f + pos;
  }

  float mx = logit;
#pragma unroll
  for (int off = 32; off >= 1; off >>= 1) mx = fmaxf(mx, __shfl_xor(mx, off, 64));
  float e = __expf(logit - mx);            // lanes >= 27: exp(-inf) = 0
  float sum = e;
#pragma unroll
  for (int off = 32; off >= 1; off >>= 1) sum += __shfl_xor(sum, off, 64);
  const float wgt = e / sum;
  uint32_t hw = (uint32_t)f16b(wgt);                       // lanes>=27 -> 0
  uint32_t nw = (uint32_t)__shfl_down((int)hw, 1, 64);     // next lane's weight
  if ((lane & 1) == 0 && lane < 28)
    s_wp[wave][lane >> 1] = hw | (nw << 16);

  __half2 out2 = u2h2(0u);
#pragma unroll
  for (int p2 = 0; p2 < 14; p2++) {
    __half2 v2 = u2h2(vpair[wave][p2][lane]);
    __half2 w2 = u2h2(s_wp[wave][p2]);
    out2 = __hfma2(w2, v2, out2);
  }
  float out = __half2float(out2.x) + __half2float(out2.y);
  attb16[(size_t)n * 512 + h * 64 + lane] = f16b(out);
}

// ============ Kernel 5: proj GEMM via MFMA f16: out = attb @ w_proj^T + b ============
__global__ __launch_bounds__(256) void k_proj(const ushort_t* __restrict__ Ah,
                                              const ushort_t* __restrict__ Bth,
                                              const float* __restrict__ bias,
                                              float* __restrict__ out) {
  __shared__ __align__(16) ushort_t As[128 * 32];
  __shared__ __align__(16) ushort_t Bs[128 * 32];
  const int tid = threadIdx.x;
  const int wave = tid >> 6, lane = tid & 63;
  const int wr = wave >> 1, wc = wave & 1;
  const int m15 = lane & 15, quad = lane >> 4;
  const int bm = blockIdx.x, bn = blockIdx.y;
  floatx4 acc[4][4];
#pragma unroll
  for (int i = 0; i < 4; i++)
#pragma unroll
    for (int j = 0; j < 4; j++) acc[i][j] = {0.f, 0.f, 0.f, 0.f};

  const int r0 = tid >> 2, c0 = (tid & 3) * 8;
  const int r1 = r0 + 64;
  for (int k0 = 0; k0 < 512; k0 += 32) {
    *(uint4*)&As[r0 * 32 + c0] = *(const uint4*)&Ah[(size_t)(bm * 128 + r0) * 512 + k0 + c0];
    *(uint4*)&As[r1 * 32 + c0] = *(const uint4*)&Ah[(size_t)(bm * 128 + r1) * 512 + k0 + c0];
    *(uint4*)&Bs[r0 * 32 + c0] = *(const uint4*)&Bth[(size_t)(bn * 128 + r0) * 512 + k0 + c0];
    *(uint4*)&Bs[r1 * 32 + c0] = *(const uint4*)&Bth[(size_t)(bn * 128 + r1) * 512 + k0 + c0];
    __syncthreads();
    half8 af[4], bf[4];
#pragma unroll
    for (int i = 0; i < 4; i++)
      af[i] = *(const half8*)&As[(wr * 64 + i * 16 + m15) * 32 + quad * 8];
#pragma unroll
    for (int j = 0; j < 4; j++)
      bf[j] = *(const half8*)&Bs[(wc * 64 + j * 16 + m15) * 32 + quad * 8];
#pragma unroll
    for (int i = 0; i < 4; i++)
#pragma unroll
      for (int j = 0; j < 4; j++)
        acc[i][j] = __builtin_amdgcn_mfma_f32_16x16x32_f16(af[i], bf[j], acc[i][j], 0, 0, 0);
    __syncthreads();
  }

#pragma unroll
  for (int i = 0; i < 4; i++)
#pragma unroll
    for (int j = 0; j < 4; j++) {
      int col = bn * 128 + wc * 64 + j * 16 + m15;
      float b = bias[col];
#pragma unroll
      for (int r = 0; r < 4; r++) {
        int row = bm * 128 + wr * 64 + i * 16 + quad * 4 + r;
        out[(size_t)row * 512 + col] = acc[i][j][r] + b;
      }
    }
}

extern "C" void kernel_launch(void* const* d_in, const int* in_sizes, int n_in,
                              void* d_out, int out_size, void* d_ws, size_t ws_size,
                              hipStream_t stream) {
  const float* x      = (const float*)d_in[0];
  const float* w_qkv  = (const float*)d_in[1];
  const float* w_proj = (const float*)d_in[2];
  const float* b_proj = (const float*)d_in[3];
  const float* w_off  = (const float*)d_in[4];
  const float* rel_d  = (const float*)d_in[5];
  const float* rel_h  = (const float*)d_in[6];
  const float* rel_w  = (const float*)d_in[7];

  char* ws = (char*)d_ws;
  uint32_t* kvb    = (uint32_t*)ws; ws += (size_t)NH * NTOK * 64 * 4;
  float*    ob     = (float*)ws;    ws += (size_t)NH * NTOK * 81 * 4;
  float*    Pb     = (float*)ws;    ws += (size_t)NH * NTOK * 126 * 4;
  ushort_t* attb16 = (ushort_t*)ws; ws += (size_t)NTOK * CDIM * 2;
  ushort_t* xh     = (ushort_t*)ws; ws += (size_t)NTOK * CDIM * 2;
  ushort_t* wqh    = (ushort_t*)ws; ws += (size_t)3 * CDIM * CDIM * 2;
  ushort_t* wph    = (ushort_t*)ws; ws += (size_t)CDIM * CDIM * 2;
  ushort_t* qh16   = (ushort_t*)ws; ws += (size_t)NH * NTOK * 64 * 2;
  ushort_t* w_offh = (ushort_t*)ws; ws += (size_t)128 * 64 * 2;
  ushort_t* relh   = (ushort_t*)ws; ws += (size_t)128 * 64 * 2;
  float*    out    = (float*)d_out;

  k_cvt  <<<dim3(3072), dim3(256), 0, stream>>>((const float4*)x, (const float4*)w_qkv,
                                                (const float4*)w_proj, xh, wqh, wph);
  k_cvt2 <<<dim3(64),   dim3(256), 0, stream>>>(w_off, rel_d, rel_h, rel_w, w_offh, relh);
  k_qkv  <<<dim3(32, 12), dim3(256), 0, stream>>>(xh, wqh, qh16, kvb);
  k_offmm<<<dim3(32, 8),  dim3(256), 0, stream>>>(xh, w_offh, ob);
  k_posmm<<<dim3(32, 8),  dim3(256), 0, stream>>>(qh16, relh, Pb);
  k_attn <<<dim3(8192),   dim3(256), 0, stream>>>(qh16, kvb, ob, Pb, attb16);
  k_proj <<<dim3(32, 4),  dim3(256), 0, stream>>>(attb16, wph, b_proj, out);
}